// Round 2
// baseline (771.758 us; speedup 1.0000x reference)
//
#include <hip/hip_runtime.h>
#include <stdint.h>

typedef __attribute__((ext_vector_type(8))) short bf16x8;
typedef __attribute__((ext_vector_type(4))) short bf16x4;
typedef __attribute__((ext_vector_type(4))) float f32x4;

#define S_LEN 2048
#define HIDDEN 2048
#define N_HEADS 32
#define N_KV 8
#define HEAD_DIM 64

__device__ __forceinline__ float bf2f(short u) {
  return __builtin_bit_cast(float, ((unsigned)(unsigned short)u) << 16);
}
__device__ __forceinline__ short f2bf(float f) {
  unsigned u = __builtin_bit_cast(unsigned, f);
  u += 0x7FFFu + ((u >> 16) & 1u);
  return (short)(u >> 16);
}
__device__ __forceinline__ bf16x8 cvt8(f32x4 lo, f32x4 hi) {
  bf16x8 r;
#pragma unroll
  for (int j = 0; j < 4; ++j) { r[j] = f2bf(lo[j]); r[j + 4] = f2bf(hi[j]); }
  return r;
}
__device__ __forceinline__ void storeC(float* p, float v) { *p = v; }
__device__ __forceinline__ void storeC(short* p, float v) { *p = f2bf(v); }

// ---------------------------------------------------------------------------
// C[M,N] = A[M,K] @ W[N,K]^T  (torch Linear). A: fp32 or bf16; W: fp32;
// C: fp32 or bf16. fp32->bf16 RNE on staging, MFMA bf16, fp32 accum.
// 128x128 tile, BK=32, 4 waves (2x2), each wave 64x64 (4x4 frags).
// LDS stride 40 elems (80B): conflict-free b128 reads/writes (5 coprime 8).
// ---------------------------------------------------------------------------
template <typename AT, typename CT>
__launch_bounds__(256, 2)
__global__ void gemm_bt(const AT* __restrict__ A, const float* __restrict__ W,
                        CT* __restrict__ C, int M, int N, int K) {
  __shared__ short As[128][40];
  __shared__ short Ws[128][40];
  const int tid  = threadIdx.x;
  const int lane = tid & 63;
  const int wid  = tid >> 6;
  const int wm = wid >> 1, wn = wid & 1;
  const int lr = lane & 15, lg = lane >> 4;
  const int m0 = blockIdx.y * 128, n0 = blockIdx.x * 128;
  const int srow = tid >> 2;           // 0..63
  const int scol = (tid & 3) * 8;      // 0,8,16,24

  f32x4 acc[4][4] = {};

  const AT*    Ap = A + (size_t)(m0 + srow) * K + scol;
  const float* Wp = W + (size_t)(n0 + srow) * K + scol;

  for (int k0 = 0; k0 < K; k0 += 32) {
    bf16x8 a0, a1, b0, b1;
    if constexpr (sizeof(AT) == 4) {
      a0 = cvt8(*(const f32x4*)(Ap + k0),
                *(const f32x4*)(Ap + k0 + 4));
      a1 = cvt8(*(const f32x4*)(Ap + (size_t)64 * K + k0),
                *(const f32x4*)(Ap + (size_t)64 * K + k0 + 4));
    } else {
      a0 = *(const bf16x8*)(Ap + k0);
      a1 = *(const bf16x8*)(Ap + (size_t)64 * K + k0);
    }
    b0 = cvt8(*(const f32x4*)(Wp + k0),
              *(const f32x4*)(Wp + k0 + 4));
    b1 = cvt8(*(const f32x4*)(Wp + (size_t)64 * K + k0),
              *(const f32x4*)(Wp + (size_t)64 * K + k0 + 4));
    __syncthreads();
    *(bf16x8*)&As[srow][scol]      = a0;
    *(bf16x8*)&As[srow + 64][scol] = a1;
    *(bf16x8*)&Ws[srow][scol]      = b0;
    *(bf16x8*)&Ws[srow + 64][scol] = b1;
    __syncthreads();
    bf16x8 af[4], bfr[4];
#pragma unroll
    for (int i = 0; i < 4; ++i) {
      af[i]  = *(const bf16x8*)&As[wm * 64 + i * 16 + lr][lg * 8];
      bfr[i] = *(const bf16x8*)&Ws[wn * 64 + i * 16 + lr][lg * 8];
    }
#pragma unroll
    for (int i = 0; i < 4; ++i)
#pragma unroll
      for (int j = 0; j < 4; ++j)
        acc[i][j] = __builtin_amdgcn_mfma_f32_16x16x32_bf16(af[i], bfr[j], acc[i][j], 0, 0, 0);
  }

#pragma unroll
  for (int i = 0; i < 4; ++i) {
#pragma unroll
    for (int j = 0; j < 4; ++j) {
      const int row = m0 + wm * 64 + i * 16 + lg * 4;
      const int col = n0 + wn * 64 + j * 16 + lr;
#pragma unroll
      for (int r = 0; r < 4; ++r)
        storeC(&C[(size_t)(row + r) * N + col], acc[i][j][r]);
    }
  }
}

// ---------------------------------------------------------------------------
// In-place RoPE on [rows, nh*64] bf16 buffer. pos = row % S_LEN.
// Pair (d, d+32): out1 = x1*c - x2*s ; out2 = x2*c + x1*s
// ---------------------------------------------------------------------------
__global__ void rope_kernel(short* __restrict__ buf, int total, int nh, int hbits) {
  int idx = blockIdx.x * 256 + threadIdx.x;
  if (idx >= total) return;
  const int i   = idx & 31;
  const int h   = (idx >> 5) & (nh - 1);
  const int row = idx >> (5 + hbits);
  const int pos = row & (S_LEN - 1);
  // inv_freq = 10000^(-i/32) = 2^(-i*log2(10000)/32)
  const float invf = exp2f(-(float)i * (13.287712379549449f / 32.0f));
  const float ang  = (float)pos * invf;
  float sn, c;
  sincosf(ang, &sn, &c);
  size_t base = (size_t)row * ((size_t)nh * HEAD_DIM) + (size_t)h * HEAD_DIM;
  float x1 = bf2f(buf[base + i]);
  float x2 = bf2f(buf[base + i + 32]);
  buf[base + i]      = f2bf(x1 * c - x2 * sn);
  buf[base + i + 32] = f2bf(x2 * c + x1 * sn);
}

// ---------------------------------------------------------------------------
// Flash attention, non-causal. Grid (qtile=32, head=32, batch=2), 256 thr.
// Each wave: 16 q-rows. K B-frags direct from global (K/V are L2-resident:
// 2x 4MB per batch). V staged transposed into LDS [d][kc] so PV B-frags are
// contiguous; P staged per-wave in LDS; online softmax in registers.
// ---------------------------------------------------------------------------
__launch_bounds__(256, 2)
__global__ void attn_kernel(const short* __restrict__ Q, const short* __restrict__ K,
                            const short* __restrict__ V, short* __restrict__ O) {
  const int qt = blockIdx.x, h = blockIdx.y, b = blockIdx.z;
  const int kv = h >> 2;
  const int tid  = threadIdx.x;
  const int lane = tid & 63, w = tid >> 6;
  const int lr = lane & 15, lg = lane >> 4;

  __shared__ short Vt[64][68];      // [d][kc]
  __shared__ short Pl[4][16][68];   // per-wave [q][kc]

  // Q A-frags (held for whole kernel), rows q0+lr, k = d
  const int q0 = qt * 64 + w * 16;
  bf16x8 qa[2];
  {
    const short* qp = Q + ((size_t)(b * S_LEN + q0 + lr)) * HIDDEN + h * HEAD_DIM + lg * 8;
    qa[0] = *(const bf16x8*)qp;
    qa[1] = *(const bf16x8*)(qp + 32);
  }

  f32x4 o[4] = {};                          // [d-frag], rows 4*lg+r
  float mrow[4] = {-1e30f, -1e30f, -1e30f, -1e30f};
  float lrow[4] = {0.f, 0.f, 0.f, 0.f};

  const int vkc = tid & 63;
  const int vdb = (tid >> 6) * 16;
  const short* vbase = V + ((size_t)(b * S_LEN) + vkc) * (N_KV * HEAD_DIM) + kv * HEAD_DIM + vdb;

  for (int kt = 0; kt < S_LEN / 64; ++kt) {
    __syncthreads();  // protect Vt from previous iteration's readers
    // ---- stage V tile transposed ----
    {
      const short* vp = vbase + (size_t)kt * 64 * (N_KV * HEAD_DIM);
      bf16x8 v0 = *(const bf16x8*)vp;
      bf16x8 v1 = *(const bf16x8*)(vp + 8);
#pragma unroll
      for (int j = 0; j < 8; ++j) Vt[vdb + j][vkc] = v0[j];
#pragma unroll
      for (int j = 0; j < 8; ++j) Vt[vdb + 8 + j][vkc] = v1[j];
    }
    // ---- QK^T (K B-frags direct from global) ----
    f32x4 sf[4];
    const short* kp = K + ((size_t)(b * S_LEN + kt * 64 + lr)) * (N_KV * HEAD_DIM)
                        + kv * HEAD_DIM + lg * 8;
#pragma unroll
    for (int nf = 0; nf < 4; ++nf) {
      bf16x8 k0 = *(const bf16x8*)(kp + (size_t)nf * 16 * (N_KV * HEAD_DIM));
      bf16x8 k1 = *(const bf16x8*)(kp + (size_t)nf * 16 * (N_KV * HEAD_DIM) + 32);
      f32x4 t = {};
      t = __builtin_amdgcn_mfma_f32_16x16x32_bf16(qa[0], k0, t, 0, 0, 0);
      t = __builtin_amdgcn_mfma_f32_16x16x32_bf16(qa[1], k1, t, 0, 0, 0);
      sf[nf] = t;
    }
    __syncthreads();  // V tile staged

    // ---- online softmax (rows 4*lg+r, cols nf*16+lr) ----
    float p[4][4];
#pragma unroll
    for (int r = 0; r < 4; ++r) {
      float mx = -1e30f;
#pragma unroll
      for (int nf = 0; nf < 4; ++nf) {
        sf[nf][r] *= 0.125f;                  // HD^-0.5, exact
        mx = fmaxf(mx, sf[nf][r]);
      }
      mx = fmaxf(mx, __shfl_xor(mx, 1, 16));
      mx = fmaxf(mx, __shfl_xor(mx, 2, 16));
      mx = fmaxf(mx, __shfl_xor(mx, 4, 16));
      mx = fmaxf(mx, __shfl_xor(mx, 8, 16));
      const float mnew = fmaxf(mrow[r], mx);
      const float alpha = expf(mrow[r] - mnew);
      float sum = 0.f;
#pragma unroll
      for (int nf = 0; nf < 4; ++nf) {
        float pv = expf(sf[nf][r] - mnew);
        p[nf][r] = pv;
        sum += pv;
      }
      sum += __shfl_xor(sum, 1, 16);
      sum += __shfl_xor(sum, 2, 16);
      sum += __shfl_xor(sum, 4, 16);
      sum += __shfl_xor(sum, 8, 16);
      lrow[r] = lrow[r] * alpha + sum;
      mrow[r] = mnew;
#pragma unroll
      for (int df = 0; df < 4; ++df) o[df][r] *= alpha;
    }
    // ---- write P (bf16) to per-wave LDS ----
#pragma unroll
    for (int nf = 0; nf < 4; ++nf)
#pragma unroll
      for (int r = 0; r < 4; ++r)
        Pl[w][lg * 4 + r][nf * 16 + lr] = f2bf(p[nf][r]);

    // ---- PV: o[df] += P[16x64] @ V[64x64] ----
#pragma unroll
    for (int ks = 0; ks < 2; ++ks) {
      const short* pp = &Pl[w][lr][lg * 8 + ks * 32];
      bf16x4 plo = *(const bf16x4*)pp;
      bf16x4 phi = *(const bf16x4*)(pp + 4);
      bf16x8 pa;
#pragma unroll
      for (int j = 0; j < 4; ++j) { pa[j] = plo[j]; pa[j + 4] = phi[j]; }
#pragma unroll
      for (int df = 0; df < 4; ++df) {
        const short* vp2 = &Vt[lr + 16 * df][lg * 8 + ks * 32];
        bf16x4 vlo = *(const bf16x4*)vp2;
        bf16x4 vhi = *(const bf16x4*)(vp2 + 4);
        bf16x8 vb;
#pragma unroll
        for (int j = 0; j < 4; ++j) { vb[j] = vlo[j]; vb[j + 4] = vhi[j]; }
        o[df] = __builtin_amdgcn_mfma_f32_16x16x32_bf16(pa, vb, o[df], 0, 0, 0);
      }
    }
  }

  // ---- epilogue: O /= l, write [b, q, h*64+d] bf16 ----
#pragma unroll
  for (int r = 0; r < 4; ++r) {
    const float inv_l = 1.0f / lrow[r];
    const int q = q0 + lg * 4 + r;
#pragma unroll
    for (int df = 0; df < 4; ++df) {
      const int d = df * 16 + lr;
      O[((size_t)(b * S_LEN) + q) * HIDDEN + h * HEAD_DIM + d] = f2bf(o[df][r] * inv_l);
    }
  }
}

// ---------------------------------------------------------------------------
extern "C" void kernel_launch(void* const* d_in, const int* in_sizes, int n_in,
                              void* d_out, int out_size, void* d_ws, size_t ws_size,
                              hipStream_t stream) {
  (void)in_sizes; (void)n_in; (void)out_size; (void)ws_size;
  const float* hidden = (const float*)d_in[0];
  const float* wq = (const float*)d_in[1];
  const float* wk = (const float*)d_in[2];
  const float* wv = (const float*)d_in[3];
  const float* wo = (const float*)d_in[4];
  float* out = (float*)d_out;

  const int M = 2 * S_LEN;  // 4096 rows (B*S)
  short* Qb = (short*)d_ws;                       // [4096, 2048] bf16
  short* Kb = Qb + (size_t)M * HIDDEN;            // [4096, 512]  bf16
  short* Vb = Kb + (size_t)M * (N_KV * HEAD_DIM); // [4096, 512]  bf16
  short* AO = Vb + (size_t)M * (N_KV * HEAD_DIM); // [4096, 2048] bf16

  // projections (fp32 in -> bf16 out)
  gemm_bt<float, short><<<dim3(16, 32), 256, 0, stream>>>(hidden, wq, Qb, M, HIDDEN, HIDDEN);
  gemm_bt<float, short><<<dim3(4, 32), 256, 0, stream>>>(hidden, wk, Kb, M, N_KV * HEAD_DIM, HIDDEN);
  gemm_bt<float, short><<<dim3(4, 32), 256, 0, stream>>>(hidden, wv, Vb, M, N_KV * HEAD_DIM, HIDDEN);
  // rope (in place, bf16)
  rope_kernel<<<(M * N_HEADS * 32) / 256, 256, 0, stream>>>(Qb, M * N_HEADS * 32, N_HEADS, 5);
  rope_kernel<<<(M * N_KV * 32) / 256, 256, 0, stream>>>(Kb, M * N_KV * 32, N_KV, 3);
  // attention (bf16 in/out)
  attn_kernel<<<dim3(S_LEN / 64, N_HEADS, 2), 256, 0, stream>>>(Qb, Kb, Vb, AO);
  // output projection (bf16 A, fp32 out)
  gemm_bt<short, float><<<dim3(16, 32), 256, 0, stream>>>(AO, wo, out, M, HIDDEN, HIDDEN);
}

// Round 3
// 477.576 us; speedup vs baseline: 1.6160x; 1.6160x over previous
//
#include <hip/hip_runtime.h>
#include <stdint.h>

typedef __attribute__((ext_vector_type(8))) short bf16x8;
typedef __attribute__((ext_vector_type(4))) short bf16x4;
typedef __attribute__((ext_vector_type(4))) float f32x4;

#define S_LEN 2048
#define HIDDEN 2048
#define N_HEADS 32
#define N_KV 8
#define HEAD_DIM 64
#define KVD (N_KV * HEAD_DIM)   // 512

__device__ __forceinline__ float bf2f(short u) {
  return __builtin_bit_cast(float, ((unsigned)(unsigned short)u) << 16);
}
__device__ __forceinline__ short f2bf(float f) {
  unsigned u = __builtin_bit_cast(unsigned, f);
  u += 0x7FFFu + ((u >> 16) & 1u);
  return (short)(u >> 16);
}
__device__ __forceinline__ bf16x8 cvt8(f32x4 lo, f32x4 hi) {
  bf16x8 r;
#pragma unroll
  for (int j = 0; j < 4; ++j) { r[j] = f2bf(lo[j]); r[j + 4] = f2bf(hi[j]); }
  return r;
}
__device__ __forceinline__ void storeC(float* p, float v) { *p = v; }
__device__ __forceinline__ void storeC(short* p, float v) { *p = f2bf(v); }

__device__ __forceinline__ void gll16(const void* g, void* l) {
  __builtin_amdgcn_global_load_lds(
      (const __attribute__((address_space(1))) void*)g,
      (__attribute__((address_space(3))) void*)l, 16, 0, 0);
}

// ---------------------------------------------------------------------------
// fp32 -> bf16 bulk convert, 5 segments, grid-stride, float4 units.
// ---------------------------------------------------------------------------
struct CvtArgs {
  const float* src[5];
  short* dst[5];
  int cnt4[5];   // float4 units per segment
};
__global__ void cvt_bf16(CvtArgs a, int total4) {
  int u = blockIdx.x * 256 + threadIdx.x;
  const int stride = gridDim.x * 256;
  for (; u < total4; u += stride) {
    int s = 0, off = u;
    while (off >= a.cnt4[s]) { off -= a.cnt4[s]; ++s; }
    f32x4 v = *(const f32x4*)(a.src[s] + (size_t)off * 4);
    bf16x4 r;
#pragma unroll
    for (int j = 0; j < 4; ++j) r[j] = f2bf(v[j]);
    *(bf16x4*)(a.dst[s] + (size_t)off * 4) = r;
  }
}

// ---------------------------------------------------------------------------
// FAST GEMM (m97 structure): C[M,N] = A[M,K] @ W[N,K]^T, A/W bf16, C bf16/fp32.
// 128x128 tile, BK=32, 4 waves (2x2). Linear LDS [128][32] staged with
// global_load_lds width=16 (4 calls/iter). 64B rows -> frag ds_read_b128
// bank-starts spread over 8 quads (near-optimal, no swizzle needed).
// ---------------------------------------------------------------------------
template <typename CT>
__launch_bounds__(256, 3)
__global__ void gemm_lds(const short* __restrict__ A, const short* __restrict__ W,
                         CT* __restrict__ C, int M, int N, int K) {
  __shared__ short As[128 * 32];
  __shared__ short Ws[128 * 32];
  const int tid  = threadIdx.x;
  const int lane = tid & 63;
  const int w    = tid >> 6;
  const int wm = w >> 1, wn = w & 1;
  const int lr = lane & 15, lg = lane >> 4;
  const int m0 = blockIdx.y * 128, n0 = blockIdx.x * 128;

  // staging map: wave w, call j covers tile rows (w+4j)*16 .. +15
  // lane l -> row +(l>>2), col bytes (l&3)*16
  const size_t a0 = (size_t)(m0 + w * 16 + (lane >> 2)) * K + (lane & 3) * 8;
  const size_t a1 = a0 + (size_t)64 * K;
  const size_t b0 = (size_t)(n0 + w * 16 + (lane >> 2)) * K + (lane & 3) * 8;
  const size_t b1 = b0 + (size_t)64 * K;
  short* lA0 = &As[(w * 16) * 32];
  short* lA1 = &As[(64 + w * 16) * 32];
  short* lB0 = &Ws[(w * 16) * 32];
  short* lB1 = &Ws[(64 + w * 16) * 32];

  f32x4 acc[4][4] = {};

  for (int k0 = 0; k0 < K; k0 += 32) {
    __syncthreads();                 // previous iter's frag reads done
    gll16(A + a0 + k0, lA0);
    gll16(A + a1 + k0, lA1);
    gll16(W + b0 + k0, lB0);
    gll16(W + b1 + k0, lB1);
    __syncthreads();                 // staging drained (compiler vmcnt(0))
    bf16x8 af[4], bfr[4];
#pragma unroll
    for (int i = 0; i < 4; ++i) {
      af[i]  = *(const bf16x8*)&As[(wm * 64 + i * 16 + lr) * 32 + lg * 8];
      bfr[i] = *(const bf16x8*)&Ws[(wn * 64 + i * 16 + lr) * 32 + lg * 8];
    }
#pragma unroll
    for (int i = 0; i < 4; ++i)
#pragma unroll
      for (int j = 0; j < 4; ++j)
        acc[i][j] = __builtin_amdgcn_mfma_f32_16x16x32_bf16(af[i], bfr[j], acc[i][j], 0, 0, 0);
  }

#pragma unroll
  for (int i = 0; i < 4; ++i) {
#pragma unroll
    for (int j = 0; j < 4; ++j) {
      const int row = m0 + wm * 64 + i * 16 + lg * 4;
      const int col = n0 + wn * 64 + j * 16 + lr;
#pragma unroll
      for (int r = 0; r < 4; ++r)
        storeC(&C[(size_t)(row + r) * N + col], acc[i][j][r]);
    }
  }
}

// ---------------------------------------------------------------------------
// FALLBACK GEMM (round-1, register-staged, converts fp32 in flight).
// ---------------------------------------------------------------------------
template <typename AT, typename CT>
__launch_bounds__(256, 2)
__global__ void gemm_bt(const AT* __restrict__ A, const float* __restrict__ W,
                        CT* __restrict__ C, int M, int N, int K) {
  __shared__ short As[128][40];
  __shared__ short Ws[128][40];
  const int tid  = threadIdx.x;
  const int lane = tid & 63;
  const int wid  = tid >> 6;
  const int wm = wid >> 1, wn = wid & 1;
  const int lr = lane & 15, lg = lane >> 4;
  const int m0 = blockIdx.y * 128, n0 = blockIdx.x * 128;
  const int srow = tid >> 2;
  const int scol = (tid & 3) * 8;

  f32x4 acc[4][4] = {};
  const AT*    Ap = A + (size_t)(m0 + srow) * K + scol;
  const float* Wp = W + (size_t)(n0 + srow) * K + scol;

  for (int k0 = 0; k0 < K; k0 += 32) {
    bf16x8 a0, a1, b0, b1;
    if constexpr (sizeof(AT) == 4) {
      a0 = cvt8(*(const f32x4*)(Ap + k0), *(const f32x4*)(Ap + k0 + 4));
      a1 = cvt8(*(const f32x4*)(Ap + (size_t)64 * K + k0),
                *(const f32x4*)(Ap + (size_t)64 * K + k0 + 4));
    } else {
      a0 = *(const bf16x8*)(Ap + k0);
      a1 = *(const bf16x8*)(Ap + (size_t)64 * K + k0);
    }
    b0 = cvt8(*(const f32x4*)(Wp + k0), *(const f32x4*)(Wp + k0 + 4));
    b1 = cvt8(*(const f32x4*)(Wp + (size_t)64 * K + k0),
              *(const f32x4*)(Wp + (size_t)64 * K + k0 + 4));
    __syncthreads();
    *(bf16x8*)&As[srow][scol]      = a0;
    *(bf16x8*)&As[srow + 64][scol] = a1;
    *(bf16x8*)&Ws[srow][scol]      = b0;
    *(bf16x8*)&Ws[srow + 64][scol] = b1;
    __syncthreads();
    bf16x8 af[4], bfr[4];
#pragma unroll
    for (int i = 0; i < 4; ++i) {
      af[i]  = *(const bf16x8*)&As[wm * 64 + i * 16 + lr][lg * 8];
      bfr[i] = *(const bf16x8*)&Ws[wn * 64 + i * 16 + lr][lg * 8];
    }
#pragma unroll
    for (int i = 0; i < 4; ++i)
#pragma unroll
      for (int j = 0; j < 4; ++j)
        acc[i][j] = __builtin_amdgcn_mfma_f32_16x16x32_bf16(af[i], bfr[j], acc[i][j], 0, 0, 0);
  }
#pragma unroll
  for (int i = 0; i < 4; ++i)
#pragma unroll
    for (int j = 0; j < 4; ++j) {
      const int row = m0 + wm * 64 + i * 16 + lg * 4;
      const int col = n0 + wn * 64 + j * 16 + lr;
#pragma unroll
      for (int r = 0; r < 4; ++r)
        storeC(&C[(size_t)(row + r) * N + col], acc[i][j][r]);
    }
}

// ---------------------------------------------------------------------------
// In-place RoPE on [rows, nh*64] bf16 buffer. pos = row % S_LEN.
// ---------------------------------------------------------------------------
__global__ void rope_kernel(short* __restrict__ buf, int total, int nh, int hbits) {
  int idx = blockIdx.x * 256 + threadIdx.x;
  if (idx >= total) return;
  const int i   = idx & 31;
  const int h   = (idx >> 5) & (nh - 1);
  const int row = idx >> (5 + hbits);
  const int pos = row & (S_LEN - 1);
  const float invf = exp2f(-(float)i * (13.287712379549449f / 32.0f));
  const float ang  = (float)pos * invf;
  float sn, c;
  sincosf(ang, &sn, &c);
  size_t base = (size_t)row * ((size_t)nh * HEAD_DIM) + (size_t)h * HEAD_DIM;
  float x1 = bf2f(buf[base + i]);
  float x2 = bf2f(buf[base + i + 32]);
  buf[base + i]      = f2bf(x1 * c - x2 * sn);
  buf[base + i + 32] = f2bf(x2 * c + x1 * sn);
}

// ---------------------------------------------------------------------------
// Flash attention, non-causal. Grid (S/128, NH, B), 256 thr = 4 waves.
// Wave owns 32 q-rows (2 row-frags). KVBLK=64. V double-buffered in LDS
// (transposed, stride 72 for aligned b128 reads), prefetched one tile ahead
// into registers. K B-frags direct from global (L2-resident). exp2-domain
// online softmax. One barrier per K-tile.
// ---------------------------------------------------------------------------
__launch_bounds__(256, 3)
__global__ void attn_kernel(const short* __restrict__ Q, const short* __restrict__ K,
                            const short* __restrict__ V, short* __restrict__ O) {
  const int qt = blockIdx.x, h = blockIdx.y, b = blockIdx.z;
  const int kv = h >> 2;
  const int tid  = threadIdx.x;
  const int lane = tid & 63, w = tid >> 6;
  const int lr = lane & 15, lg = lane >> 4;

  __shared__ short Vt[2][64][72];   // [buf][d][kc]
  __shared__ short Pl[4][32][72];   // per-wave [q][kc]

  const int q0 = qt * 128 + w * 32;
  bf16x8 qa[2][2];
#pragma unroll
  for (int fr = 0; fr < 2; ++fr) {
    const short* qp = Q + ((size_t)(b * S_LEN + q0 + fr * 16 + lr)) * HIDDEN
                        + h * HEAD_DIM + lg * 8;
    qa[fr][0] = *(const bf16x8*)qp;
    qa[fr][1] = *(const bf16x8*)(qp + 32);
  }

  f32x4 o[2][4] = {};
  float mrow[2][4], lrow[2][4];
#pragma unroll
  for (int fr = 0; fr < 2; ++fr)
#pragma unroll
    for (int r = 0; r < 4; ++r) { mrow[fr][r] = -1e30f; lrow[fr][r] = 0.f; }

  // V prefetch: thread loads V[kt*64 + lane][w*16 .. w*16+15]
  const int vdb = w * 16;
  const short* vbase = V + ((size_t)(b * S_LEN) + lane) * KVD + kv * HEAD_DIM + vdb;
  bf16x8 vp0 = *(const bf16x8*)vbase;
  bf16x8 vp1 = *(const bf16x8*)(vbase + 8);

  // exp2-domain scale: HD^-0.5 * log2(e)
  const float SC = 0.125f * 1.4426950408889634f;

  for (int kt = 0; kt < S_LEN / 64; ++kt) {
    const int cur = kt & 1;
    // ---- write staged V (transposed) ----
#pragma unroll
    for (int j = 0; j < 8; ++j) Vt[cur][vdb + j][lane] = vp0[j];
#pragma unroll
    for (int j = 0; j < 8; ++j) Vt[cur][vdb + 8 + j][lane] = vp1[j];
    __syncthreads();
    // ---- prefetch next V tile into regs (hides under QK^T+softmax) ----
    if (kt + 1 < S_LEN / 64) {
      const short* vp = vbase + (size_t)(kt + 1) * 64 * KVD;
      vp0 = *(const bf16x8*)vp;
      vp1 = *(const bf16x8*)(vp + 8);
    }
    // ---- QK^T ----
    f32x4 sf[2][4];
    const short* kp = K + ((size_t)(b * S_LEN + kt * 64 + lr)) * KVD
                        + kv * HEAD_DIM + lg * 8;
#pragma unroll
    for (int nf = 0; nf < 4; ++nf) {
      bf16x8 k0 = *(const bf16x8*)(kp + (size_t)nf * 16 * KVD);
      bf16x8 k1 = *(const bf16x8*)(kp + (size_t)nf * 16 * KVD + 32);
#pragma unroll
      for (int fr = 0; fr < 2; ++fr) {
        f32x4 t = {};
        t = __builtin_amdgcn_mfma_f32_16x16x32_bf16(qa[fr][0], k0, t, 0, 0, 0);
        t = __builtin_amdgcn_mfma_f32_16x16x32_bf16(qa[fr][1], k1, t, 0, 0, 0);
        sf[fr][nf] = t;
      }
    }
    // ---- online softmax (exp2 domain), write P to per-wave LDS ----
#pragma unroll
    for (int fr = 0; fr < 2; ++fr) {
#pragma unroll
      for (int r = 0; r < 4; ++r) {
        float mx = -1e30f;
#pragma unroll
        for (int nf = 0; nf < 4; ++nf) {
          sf[fr][nf][r] *= SC;
          mx = fmaxf(mx, sf[fr][nf][r]);
        }
        mx = fmaxf(mx, __shfl_xor(mx, 1, 16));
        mx = fmaxf(mx, __shfl_xor(mx, 2, 16));
        mx = fmaxf(mx, __shfl_xor(mx, 4, 16));
        mx = fmaxf(mx, __shfl_xor(mx, 8, 16));
        const float mnew  = fmaxf(mrow[fr][r], mx);
        const float alpha = exp2f(mrow[fr][r] - mnew);
        float sum = 0.f;
#pragma unroll
        for (int nf = 0; nf < 4; ++nf) {
          float pv = exp2f(sf[fr][nf][r] - mnew);
          Pl[w][fr * 16 + lg * 4 + r][nf * 16 + lr] = f2bf(pv);
          sum += pv;
        }
        sum += __shfl_xor(sum, 1, 16);
        sum += __shfl_xor(sum, 2, 16);
        sum += __shfl_xor(sum, 4, 16);
        sum += __shfl_xor(sum, 8, 16);
        lrow[fr][r] = lrow[fr][r] * alpha + sum;
        mrow[fr][r] = mnew;
#pragma unroll
        for (int df = 0; df < 4; ++df) o[fr][df][r] *= alpha;
      }
    }
    // ---- PV: o[fr][df] += P[32x64] @ V[64x64] ----
#pragma unroll
    for (int ks = 0; ks < 2; ++ks) {
      bf16x8 vb[4];
#pragma unroll
      for (int df = 0; df < 4; ++df)
        vb[df] = *(const bf16x8*)&Vt[cur][df * 16 + lr][ks * 32 + lg * 8];
#pragma unroll
      for (int fr = 0; fr < 2; ++fr) {
        bf16x8 pa = *(const bf16x8*)&Pl[w][fr * 16 + lr][ks * 32 + lg * 8];
#pragma unroll
        for (int df = 0; df < 4; ++df)
          o[fr][df] = __builtin_amdgcn_mfma_f32_16x16x32_bf16(pa, vb[df], o[fr][df], 0, 0, 0);
      }
    }
  }

  // ---- epilogue ----
#pragma unroll
  for (int fr = 0; fr < 2; ++fr)
#pragma unroll
    for (int r = 0; r < 4; ++r) {
      const float inv_l = 1.0f / lrow[fr][r];
      const int q = q0 + fr * 16 + lg * 4 + r;
#pragma unroll
      for (int df = 0; df < 4; ++df) {
        const int d = df * 16 + lr;
        O[((size_t)(b * S_LEN) + q) * HIDDEN + h * HEAD_DIM + d] = f2bf(o[fr][df][r] * inv_l);
      }
    }
}

// ---------------------------------------------------------------------------
extern "C" void kernel_launch(void* const* d_in, const int* in_sizes, int n_in,
                              void* d_out, int out_size, void* d_ws, size_t ws_size,
                              hipStream_t stream) {
  (void)in_sizes; (void)n_in; (void)out_size;
  const float* hidden = (const float*)d_in[0];
  const float* wq = (const float*)d_in[1];
  const float* wk = (const float*)d_in[2];
  const float* wv = (const float*)d_in[3];
  const float* wo = (const float*)d_in[4];
  float* out = (float*)d_out;

  const int M = 2 * S_LEN;  // 4096
  const size_t nHid = (size_t)M * HIDDEN;        // 8388608
  const size_t nW   = (size_t)HIDDEN * HIDDEN;   // 4194304
  const size_t nWkv = (size_t)KVD * HIDDEN;      // 1048576
  const size_t nKV  = (size_t)M * KVD;           // 2097152

  const size_t fastElems = nHid + nW + 2 * nWkv + nW   // converts
                         + nHid + 2 * nKV + nHid;      // Qb,Kb,Vb,AO
  if (ws_size >= fastElems * sizeof(short)) {
    short* hb  = (short*)d_ws;
    short* wqb = hb + nHid;
    short* wkb = wqb + nW;
    short* wvb = wkb + nWkv;
    short* wob = wvb + nWkv;
    short* Qb  = wob + nW;
    short* Kb  = Qb + nHid;
    short* Vb  = Kb + nKV;
    short* AO  = Vb + nKV;

    CvtArgs ca;
    ca.src[0] = hidden; ca.dst[0] = hb;  ca.cnt4[0] = (int)(nHid / 4);
    ca.src[1] = wq;     ca.dst[1] = wqb; ca.cnt4[1] = (int)(nW / 4);
    ca.src[2] = wk;     ca.dst[2] = wkb; ca.cnt4[2] = (int)(nWkv / 4);
    ca.src[3] = wv;     ca.dst[3] = wvb; ca.cnt4[3] = (int)(nWkv / 4);
    ca.src[4] = wo;     ca.dst[4] = wob; ca.cnt4[4] = (int)(nW / 4);
    const int total4 = (int)((nHid + nW + 2 * nWkv + nW) / 4);
    cvt_bf16<<<2048, 256, 0, stream>>>(ca, total4);

    gemm_lds<short><<<dim3(16, 32), 256, 0, stream>>>(hb, wqb, Qb, M, HIDDEN, HIDDEN);
    gemm_lds<short><<<dim3(4, 32), 256, 0, stream>>>(hb, wkb, Kb, M, KVD, HIDDEN);
    gemm_lds<short><<<dim3(4, 32), 256, 0, stream>>>(hb, wvb, Vb, M, KVD, HIDDEN);
    rope_kernel<<<(M * N_HEADS * 32) / 256, 256, 0, stream>>>(Qb, M * N_HEADS * 32, N_HEADS, 5);
    rope_kernel<<<(M * N_KV * 32) / 256, 256, 0, stream>>>(Kb, M * N_KV * 32, N_KV, 3);
    attn_kernel<<<dim3(S_LEN / 128, N_HEADS, 2), 256, 0, stream>>>(Qb, Kb, Vb, AO);
    gemm_lds<float><<<dim3(16, 32), 256, 0, stream>>>(AO, wob, out, M, HIDDEN, HIDDEN);
  } else {
    short* Qb = (short*)d_ws;
    short* Kb = Qb + nHid;
    short* Vb = Kb + nKV;
    short* AO = Vb + nKV;
    gemm_bt<float, short><<<dim3(16, 32), 256, 0, stream>>>(hidden, wq, Qb, M, HIDDEN, HIDDEN);
    gemm_bt<float, short><<<dim3(4, 32), 256, 0, stream>>>(hidden, wk, Kb, M, KVD, HIDDEN);
    gemm_bt<float, short><<<dim3(4, 32), 256, 0, stream>>>(hidden, wv, Vb, M, KVD, HIDDEN);
    rope_kernel<<<(M * N_HEADS * 32) / 256, 256, 0, stream>>>(Qb, M * N_HEADS * 32, N_HEADS, 5);
    rope_kernel<<<(M * N_KV * 32) / 256, 256, 0, stream>>>(Kb, M * N_KV * 32, N_KV, 3);
    attn_kernel<<<dim3(S_LEN / 128, N_HEADS, 2), 256, 0, stream>>>(Qb, Kb, Vb, AO);
    gemm_bt<short, float><<<dim3(16, 32), 256, 0, stream>>>(AO, wo, out, M, HIDDEN, HIDDEN);
  }
}

// Round 4
// 360.713 us; speedup vs baseline: 2.1395x; 1.3240x over previous
//
#include <hip/hip_runtime.h>
#include <stdint.h>

typedef __attribute__((ext_vector_type(8))) short bf16x8;
typedef __attribute__((ext_vector_type(4))) short bf16x4;
typedef __attribute__((ext_vector_type(4))) float f32x4;

#define S_LEN 2048
#define HIDDEN 2048
#define N_HEADS 32
#define N_KV 8
#define HEAD_DIM 64
#define KVD (N_KV * HEAD_DIM)   // 512

__device__ __forceinline__ float bf2f(short u) {
  return __builtin_bit_cast(float, ((unsigned)(unsigned short)u) << 16);
}
__device__ __forceinline__ short f2bf(float f) {
  unsigned u = __builtin_bit_cast(unsigned, f);
  u += 0x7FFFu + ((u >> 16) & 1u);
  return (short)(u >> 16);
}
__device__ __forceinline__ bf16x8 cvt8(f32x4 lo, f32x4 hi) {
  bf16x8 r;
#pragma unroll
  for (int j = 0; j < 4; ++j) { r[j] = f2bf(lo[j]); r[j + 4] = f2bf(hi[j]); }
  return r;
}
__device__ __forceinline__ void storeC(float* p, float v) { *p = v; }
__device__ __forceinline__ void storeC(short* p, float v) { *p = f2bf(v); }

__device__ __forceinline__ void gll16(const void* g, void* l) {
  __builtin_amdgcn_global_load_lds(
      (const __attribute__((address_space(1))) void*)g,
      (__attribute__((address_space(3))) void*)l, 16, 0, 0);
}

// ---------------------------------------------------------------------------
// fp32 -> bf16 bulk convert, 5 segments, grid-stride, float4 units.
// ---------------------------------------------------------------------------
struct CvtArgs {
  const float* src[5];
  short* dst[5];
  int cnt4[5];
};
__global__ void cvt_bf16(CvtArgs a, int total4) {
  int u = blockIdx.x * 256 + threadIdx.x;
  const int stride = gridDim.x * 256;
  for (; u < total4; u += stride) {
    int s = 0, off = u;
    while (off >= a.cnt4[s]) { off -= a.cnt4[s]; ++s; }
    f32x4 v = *(const f32x4*)(a.src[s] + (size_t)off * 4);
    bf16x4 r;
#pragma unroll
    for (int j = 0; j < 4; ++j) r[j] = f2bf(v[j]);
    *(bf16x4*)(a.dst[s] + (size_t)off * 4) = r;
  }
}

// ---------------------------------------------------------------------------
// FAST GEMM (m97 structure): C[M,N] = A[M,K] @ W[N,K]^T, bf16 in, bf16/fp32 out.
// 128x128 tile, BK=32, global_load_lds width=16 staging, linear LDS.
// ---------------------------------------------------------------------------
template <typename CT>
__launch_bounds__(256, 3)
__global__ void gemm_lds(const short* __restrict__ A, const short* __restrict__ W,
                         CT* __restrict__ C, int M, int N, int K) {
  __shared__ short As[128 * 32];
  __shared__ short Ws[128 * 32];
  const int tid  = threadIdx.x;
  const int lane = tid & 63;
  const int w    = tid >> 6;
  const int wm = w >> 1, wn = w & 1;
  const int lr = lane & 15, lg = lane >> 4;
  const int m0 = blockIdx.y * 128, n0 = blockIdx.x * 128;

  const size_t a0 = (size_t)(m0 + w * 16 + (lane >> 2)) * K + (lane & 3) * 8;
  const size_t a1 = a0 + (size_t)64 * K;
  const size_t b0 = (size_t)(n0 + w * 16 + (lane >> 2)) * K + (lane & 3) * 8;
  const size_t b1 = b0 + (size_t)64 * K;
  short* lA0 = &As[(w * 16) * 32];
  short* lA1 = &As[(64 + w * 16) * 32];
  short* lB0 = &Ws[(w * 16) * 32];
  short* lB1 = &Ws[(64 + w * 16) * 32];

  f32x4 acc[4][4] = {};

  for (int k0 = 0; k0 < K; k0 += 32) {
    __syncthreads();
    gll16(A + a0 + k0, lA0);
    gll16(A + a1 + k0, lA1);
    gll16(W + b0 + k0, lB0);
    gll16(W + b1 + k0, lB1);
    __syncthreads();
    bf16x8 af[4], bfr[4];
#pragma unroll
    for (int i = 0; i < 4; ++i) {
      af[i]  = *(const bf16x8*)&As[(wm * 64 + i * 16 + lr) * 32 + lg * 8];
      bfr[i] = *(const bf16x8*)&Ws[(wn * 64 + i * 16 + lr) * 32 + lg * 8];
    }
#pragma unroll
    for (int i = 0; i < 4; ++i)
#pragma unroll
      for (int j = 0; j < 4; ++j)
        acc[i][j] = __builtin_amdgcn_mfma_f32_16x16x32_bf16(af[i], bfr[j], acc[i][j], 0, 0, 0);
  }

#pragma unroll
  for (int i = 0; i < 4; ++i)
#pragma unroll
    for (int j = 0; j < 4; ++j) {
      const int row = m0 + wm * 64 + i * 16 + lg * 4;
      const int col = n0 + wn * 64 + j * 16 + lr;
#pragma unroll
      for (int r = 0; r < 4; ++r)
        storeC(&C[(size_t)(row + r) * N + col], acc[i][j][r]);
    }
}

// ---------------------------------------------------------------------------
// FALLBACK GEMM (register-staged, converts fp32 in flight).
// ---------------------------------------------------------------------------
template <typename AT, typename CT>
__launch_bounds__(256, 2)
__global__ void gemm_bt(const AT* __restrict__ A, const float* __restrict__ W,
                        CT* __restrict__ C, int M, int N, int K) {
  __shared__ short As[128][40];
  __shared__ short Ws[128][40];
  const int tid  = threadIdx.x;
  const int lane = tid & 63;
  const int wid  = tid >> 6;
  const int wm = wid >> 1, wn = wid & 1;
  const int lr = lane & 15, lg = lane >> 4;
  const int m0 = blockIdx.y * 128, n0 = blockIdx.x * 128;
  const int srow = tid >> 2;
  const int scol = (tid & 3) * 8;

  f32x4 acc[4][4] = {};
  const AT*    Ap = A + (size_t)(m0 + srow) * K + scol;
  const float* Wp = W + (size_t)(n0 + srow) * K + scol;

  for (int k0 = 0; k0 < K; k0 += 32) {
    bf16x8 a0, a1, b0, b1;
    if constexpr (sizeof(AT) == 4) {
      a0 = cvt8(*(const f32x4*)(Ap + k0), *(const f32x4*)(Ap + k0 + 4));
      a1 = cvt8(*(const f32x4*)(Ap + (size_t)64 * K + k0),
                *(const f32x4*)(Ap + (size_t)64 * K + k0 + 4));
    } else {
      a0 = *(const bf16x8*)(Ap + k0);
      a1 = *(const bf16x8*)(Ap + (size_t)64 * K + k0);
    }
    b0 = cvt8(*(const f32x4*)(Wp + k0), *(const f32x4*)(Wp + k0 + 4));
    b1 = cvt8(*(const f32x4*)(Wp + (size_t)64 * K + k0),
              *(const f32x4*)(Wp + (size_t)64 * K + k0 + 4));
    __syncthreads();
    *(bf16x8*)&As[srow][scol]      = a0;
    *(bf16x8*)&As[srow + 64][scol] = a1;
    *(bf16x8*)&Ws[srow][scol]      = b0;
    *(bf16x8*)&Ws[srow + 64][scol] = b1;
    __syncthreads();
    bf16x8 af[4], bfr[4];
#pragma unroll
    for (int i = 0; i < 4; ++i) {
      af[i]  = *(const bf16x8*)&As[wm * 64 + i * 16 + lr][lg * 8];
      bfr[i] = *(const bf16x8*)&Ws[wn * 64 + i * 16 + lr][lg * 8];
    }
#pragma unroll
    for (int i = 0; i < 4; ++i)
#pragma unroll
      for (int j = 0; j < 4; ++j)
        acc[i][j] = __builtin_amdgcn_mfma_f32_16x16x32_bf16(af[i], bfr[j], acc[i][j], 0, 0, 0);
  }
#pragma unroll
  for (int i = 0; i < 4; ++i)
#pragma unroll
    for (int j = 0; j < 4; ++j) {
      const int row = m0 + wm * 64 + i * 16 + lg * 4;
      const int col = n0 + wn * 64 + j * 16 + lr;
#pragma unroll
      for (int r = 0; r < 4; ++r)
        storeC(&C[(size_t)(row + r) * N + col], acc[i][j][r]);
    }
}

// ---------------------------------------------------------------------------
// RoPE, head h -> cols 64h..64h+63 of a [rows, rowstride] bf16 buffer.
// NH=40 covers Q(32)+K(8) in the fused QKV buffer (V cols untouched).
// ---------------------------------------------------------------------------
template <int NH>
__global__ void rope_kernel(short* __restrict__ buf, int rowstride, int total) {
  int idx = blockIdx.x * 256 + threadIdx.x;
  if (idx >= total) return;
  const int i   = idx & 31;
  const int hh  = (idx >> 5) % NH;
  const int row = (idx >> 5) / NH;
  const int pos = row & (S_LEN - 1);
  const float invf = exp2f(-(float)i * (13.287712379549449f / 32.0f));
  const float ang  = (float)pos * invf;
  float sn, c;
  sincosf(ang, &sn, &c);
  size_t base = (size_t)row * rowstride + hh * 64;
  float x1 = bf2f(buf[base + i]);
  float x2 = bf2f(buf[base + i + 32]);
  buf[base + i]      = f2bf(x1 * c - x2 * sn);
  buf[base + i + 32] = f2bf(x2 * c + x1 * sn);
}

// ---------------------------------------------------------------------------
// Flash attention, double-swapped MFMA (T12-style): lane's q = lane&15 for
// QK^T output, softmax, P-frag AND PV output -> softmax fully in-register,
// no P LDS round-trip, no per-row shuffle chains.
//   QK^T: st = mfma(A=K_frag, B=Q_frag)  -> row=k_local(4lg+r), col=q(lr)
//   PV:   o  = mfma(A=V_frag, B=P_frag)  -> row=d_local(4lg+r), col=q(lr)
// P pack uses the k-slot identity: slot(lg,j) of operand k-dim maps to
// k = 32ks + 16(j>>2) + 4lg + (j&3); V columns are stored LDS-permuted with
// the same bijection so contraction pairs match.
// Grid (S/128, NH, B), 256 thr = 4 waves, wave owns 32 q-rows.
// ---------------------------------------------------------------------------
__launch_bounds__(256, 3)
__global__ void attn_kernel(const short* __restrict__ Q, const short* __restrict__ K,
                            const short* __restrict__ V, short* __restrict__ O,
                            int qs, int ks_, int os) {
  const int qt = blockIdx.x, h = blockIdx.y, b = blockIdx.z;
  const int kv = h >> 2;
  const int tid  = threadIdx.x;
  const int lane = tid & 63, w = tid >> 6;
  const int lr = lane & 15, lg = lane >> 4;

  __shared__ short Vt[2][64][72];   // [buf][d][kc-permuted]

  const int q0 = qt * 128 + w * 32;
  bf16x8 qa[2][2];
#pragma unroll
  for (int fr = 0; fr < 2; ++fr) {
    const short* qp = Q + (size_t)(b * S_LEN + q0 + fr * 16 + lr) * qs + h * HEAD_DIM + lg * 8;
    qa[fr][0] = *(const bf16x8*)qp;
    qa[fr][1] = *(const bf16x8*)(qp + 32);
  }

  f32x4 o[2][4] = {};               // [fr][df], row=d_local, col=q=lr
  float mrow[2] = {-1e30f, -1e30f};
  float lrow[2] = {0.f, 0.f};

  // V staging: thread owns k-row (kt*64+lane), d-cols vdb..vdb+15.
  // column permutation c(k): bits c5=k5, c4c3=k3k2, c2=k4, c1c0=k1k0
  const int vdb   = w * 16;
  const int cperm = (lane & 32) + ((lane >> 2) & 3) * 8 + ((lane >> 4) & 1) * 4 + (lane & 3);
  const short* vbase = V + ((size_t)(b * S_LEN) + lane) * ks_ + kv * HEAD_DIM + vdb;
  bf16x8 vp0 = *(const bf16x8*)vbase;
  bf16x8 vp1 = *(const bf16x8*)(vbase + 8);

  const float SC = 0.125f * 1.4426950408889634f;   // HD^-0.5 * log2(e)

  for (int kt = 0; kt < S_LEN / 64; ++kt) {
    const int cur = kt & 1;
    // ---- write staged V (transposed + column-permuted) ----
#pragma unroll
    for (int j = 0; j < 8; ++j) Vt[cur][vdb + j][cperm] = vp0[j];
#pragma unroll
    for (int j = 0; j < 8; ++j) Vt[cur][vdb + 8 + j][cperm] = vp1[j];
    __syncthreads();
    // ---- prefetch next V tile into regs ----
    if (kt + 1 < S_LEN / 64) {
      const short* vp = vbase + (size_t)(kt + 1) * 64 * ks_;
      vp0 = *(const bf16x8*)vp;
      vp1 = *(const bf16x8*)(vp + 8);
    }
    // ---- QK^T swapped: st[fr][nf] row=k_local col=q ----
    f32x4 sf[2][4];
    const short* kp = K + (size_t)(b * S_LEN + kt * 64 + lr) * ks_ + kv * HEAD_DIM + lg * 8;
#pragma unroll
    for (int nf = 0; nf < 4; ++nf) {
      bf16x8 k0 = *(const bf16x8*)(kp + (size_t)nf * 16 * ks_);
      bf16x8 k1 = *(const bf16x8*)(kp + (size_t)nf * 16 * ks_ + 32);
#pragma unroll
      for (int fr = 0; fr < 2; ++fr) {
        f32x4 t = (nf == 0) ? f32x4{} : f32x4{};  // fresh acc per (fr,nf)
        t = __builtin_amdgcn_mfma_f32_16x16x32_bf16(k0, qa[fr][0], t, 0, 0, 0);
        t = __builtin_amdgcn_mfma_f32_16x16x32_bf16(k1, qa[fr][1], t, 0, 0, 0);
        sf[fr][nf] = t;
      }
    }
    // ---- in-register online softmax (raw domain max, exp2 with fused scale) ----
    bf16x8 pa[2][2];
#pragma unroll
    for (int fr = 0; fr < 2; ++fr) {
      float mx = -1e30f;
#pragma unroll
      for (int nf = 0; nf < 4; ++nf)
#pragma unroll
        for (int r = 0; r < 4; ++r) mx = fmaxf(mx, sf[fr][nf][r]);
      mx = fmaxf(mx, __shfl_xor(mx, 16));
      mx = fmaxf(mx, __shfl_xor(mx, 32));
      const float mnew  = fmaxf(mrow[fr], mx);
      const float alpha = exp2f((mrow[fr] - mnew) * SC);
      mrow[fr] = mnew;
      float sum = 0.f;
#pragma unroll
      for (int nf = 0; nf < 4; ++nf)
#pragma unroll
        for (int r = 0; r < 4; ++r) {
          float pv = exp2f((sf[fr][nf][r] - mnew) * SC);
          sf[fr][nf][r] = pv;
          sum += pv;
        }
      sum += __shfl_xor(sum, 16);
      sum += __shfl_xor(sum, 32);
      lrow[fr] = lrow[fr] * alpha + sum;
#pragma unroll
      for (int df = 0; df < 4; ++df) o[fr][df] *= alpha;
      // pack P into A/B k-slot layout: slot j<4 -> tile 2ks, j>=4 -> tile 2ks+1
#pragma unroll
      for (int ks2 = 0; ks2 < 2; ++ks2)
#pragma unroll
        for (int j = 0; j < 4; ++j) {
          pa[fr][ks2][j]     = f2bf(sf[fr][2 * ks2][j]);
          pa[fr][ks2][j + 4] = f2bf(sf[fr][2 * ks2 + 1][j]);
        }
    }
    // ---- PV swapped: o += mfma(V_frag, P_frag) ----
    __builtin_amdgcn_s_setprio(1);
#pragma unroll
    for (int ks2 = 0; ks2 < 2; ++ks2) {
      bf16x8 vb[4];
#pragma unroll
      for (int df = 0; df < 4; ++df)
        vb[df] = *(const bf16x8*)&Vt[cur][df * 16 + lr][ks2 * 32 + lg * 8];
#pragma unroll
      for (int fr = 0; fr < 2; ++fr)
#pragma unroll
        for (int df = 0; df < 4; ++df)
          o[fr][df] = __builtin_amdgcn_mfma_f32_16x16x32_bf16(vb[df], pa[fr][ks2], o[fr][df], 0, 0, 0);
    }
    __builtin_amdgcn_s_setprio(0);
  }

  // ---- epilogue: lane q = lr, d = df*16 + 4lg + r (4 consecutive -> 8B store)
#pragma unroll
  for (int fr = 0; fr < 2; ++fr) {
    const float invl = 1.0f / lrow[fr];
    const size_t orow = (size_t)(b * S_LEN + q0 + fr * 16 + lr) * os + h * HEAD_DIM;
#pragma unroll
    for (int df = 0; df < 4; ++df) {
      bf16x4 pk;
#pragma unroll
      for (int r = 0; r < 4; ++r) pk[r] = f2bf(o[fr][df][r] * invl);
      *(bf16x4*)&O[orow + df * 16 + 4 * lg] = pk;
    }
  }
}

// ---------------------------------------------------------------------------
extern "C" void kernel_launch(void* const* d_in, const int* in_sizes, int n_in,
                              void* d_out, int out_size, void* d_ws, size_t ws_size,
                              hipStream_t stream) {
  (void)in_sizes; (void)n_in; (void)out_size;
  const float* hidden = (const float*)d_in[0];
  const float* wq = (const float*)d_in[1];
  const float* wk = (const float*)d_in[2];
  const float* wv = (const float*)d_in[3];
  const float* wo = (const float*)d_in[4];
  float* out = (float*)d_out;

  const int M = 2 * S_LEN;                        // 4096
  const size_t nHid  = (size_t)M * HIDDEN;        // 8388608
  const size_t nW    = (size_t)HIDDEN * HIDDEN;   // 4194304
  const size_t nWkv  = (size_t)KVD * HIDDEN;      // 1048576
  const size_t nWcat = nW + 2 * nWkv;             // 6291456  (wq|wk|wv rows)
  const int    NQKV  = HIDDEN + 2 * KVD;          // 3072
  const size_t nQKV  = (size_t)M * NQKV;          // 12582912

  const size_t fastElems = nHid + nWcat + nW + nQKV + nHid;  // 39845888
  if (ws_size >= fastElems * sizeof(short)) {
    short* hb   = (short*)d_ws;
    short* wcat = hb + nHid;          // [3072][2048]: wq rows, wk rows, wv rows
    short* wob  = wcat + nWcat;
    short* QKV  = wob + nW;           // [4096][3072]: Q | K | V
    short* AO   = QKV + nQKV;

    CvtArgs ca;
    ca.src[0] = hidden; ca.dst[0] = hb;            ca.cnt4[0] = (int)(nHid / 4);
    ca.src[1] = wq;     ca.dst[1] = wcat;          ca.cnt4[1] = (int)(nW / 4);
    ca.src[2] = wk;     ca.dst[2] = wcat + nW;     ca.cnt4[2] = (int)(nWkv / 4);
    ca.src[3] = wv;     ca.dst[3] = wcat + nW + nWkv; ca.cnt4[3] = (int)(nWkv / 4);
    ca.src[4] = wo;     ca.dst[4] = wob;           ca.cnt4[4] = (int)(nW / 4);
    const int total4 = (int)((nHid + nWcat + nW) / 4);
    cvt_bf16<<<2048, 256, 0, stream>>>(ca, total4);

    // fused QKV projection: [4096,3072] = hb @ wcat^T
    gemm_lds<short><<<dim3(NQKV / 128, 32), 256, 0, stream>>>(hb, wcat, QKV, M, NQKV, HIDDEN);
    // fused RoPE over Q(32 heads) + K(8 heads) = cols 0..2559
    const int rtot = M * 40 * 32;
    rope_kernel<40><<<(rtot + 255) / 256, 256, 0, stream>>>(QKV, NQKV, rtot);
    // attention: Q at col 0, K at col 2048, V at col 2560 of QKV
    attn_kernel<<<dim3(S_LEN / 128, N_HEADS, 2), 256, 0, stream>>>(
        QKV, QKV + HIDDEN, QKV + HIDDEN + KVD, AO, NQKV, NQKV, HIDDEN);
    // output projection
    gemm_lds<float><<<dim3(16, 32), 256, 0, stream>>>(AO, wob, out, M, HIDDEN, HIDDEN);
  } else {
    short* Qb = (short*)d_ws;
    short* Kb = Qb + nHid;
    short* Vb = Kb + (size_t)M * KVD;
    short* AO = Vb + (size_t)M * KVD;
    gemm_bt<float, short><<<dim3(16, 32), 256, 0, stream>>>(hidden, wq, Qb, M, HIDDEN, HIDDEN);
    gemm_bt<float, short><<<dim3(4, 32), 256, 0, stream>>>(hidden, wk, Kb, M, KVD, HIDDEN);
    gemm_bt<float, short><<<dim3(4, 32), 256, 0, stream>>>(hidden, wv, Vb, M, KVD, HIDDEN);
    const int rq = M * N_HEADS * 32, rk = M * N_KV * 32;
    rope_kernel<N_HEADS><<<(rq + 255) / 256, 256, 0, stream>>>(Qb, HIDDEN, rq);
    rope_kernel<N_KV><<<(rk + 255) / 256, 256, 0, stream>>>(Kb, KVD, rk);
    attn_kernel<<<dim3(S_LEN / 128, N_HEADS, 2), 256, 0, stream>>>(
        Qb, Kb, Vb, AO, HIDDEN, KVD, HIDDEN);
    gemm_bt<short, float><<<dim3(16, 32), 256, 0, stream>>>(AO, wo, out, M, HIDDEN, HIDDEN);
  }
}

// Round 5
// 300.257 us; speedup vs baseline: 2.5703x; 1.2013x over previous
//
#include <hip/hip_runtime.h>
#include <stdint.h>

typedef __attribute__((ext_vector_type(8))) short bf16x8;
typedef __attribute__((ext_vector_type(4))) short bf16x4;
typedef __attribute__((ext_vector_type(4))) float f32x4;
typedef __attribute__((ext_vector_type(4))) unsigned u32x4;
typedef __attribute__((ext_vector_type(2))) unsigned u32x2;

#define S_LEN 2048
#define HIDDEN 2048
#define N_HEADS 32
#define N_KV 8
#define HEAD_DIM 64
#define KVD (N_KV * HEAD_DIM)   // 512

__device__ __forceinline__ float bf2f(short u) {
  return __builtin_bit_cast(float, ((unsigned)(unsigned short)u) << 16);
}
__device__ __forceinline__ short f2bf(float f) {
  unsigned u = __builtin_bit_cast(unsigned, f);
  u += 0x7FFFu + ((u >> 16) & 1u);
  return (short)(u >> 16);
}
__device__ __forceinline__ unsigned cvtpk(float lo, float hi) {
  unsigned r;
  asm("v_cvt_pk_bf16_f32 %0, %1, %2" : "=v"(r) : "v"(lo), "v"(hi));
  return r;
}
__device__ __forceinline__ bf16x8 cvt8(f32x4 lo, f32x4 hi) {
  bf16x8 r;
#pragma unroll
  for (int j = 0; j < 4; ++j) { r[j] = f2bf(lo[j]); r[j + 4] = f2bf(hi[j]); }
  return r;
}
__device__ __forceinline__ void storeC(float* p, float v) { *p = v; }
__device__ __forceinline__ void storeC(short* p, float v) { *p = f2bf(v); }

__device__ __forceinline__ void gll16(const void* g, void* l) {
  __builtin_amdgcn_global_load_lds(
      (const __attribute__((address_space(1))) void*)g,
      (__attribute__((address_space(3))) void*)l, 16, 0, 0);
}

// ---------------------------------------------------------------------------
// fp32 -> bf16 bulk convert, 5 segments, grid-stride, float4 units.
// ---------------------------------------------------------------------------
struct CvtArgs {
  const float* src[5];
  short* dst[5];
  int cnt4[5];
};
__global__ void cvt_bf16(CvtArgs a, int total4) {
  int u = blockIdx.x * 256 + threadIdx.x;
  const int stride = gridDim.x * 256;
  for (; u < total4; u += stride) {
    int s = 0, off = u;
    while (off >= a.cnt4[s]) { off -= a.cnt4[s]; ++s; }
    f32x4 v = *(const f32x4*)(a.src[s] + (size_t)off * 4);
    bf16x4 r;
#pragma unroll
    for (int j = 0; j < 4; ++j) r[j] = f2bf(v[j]);
    *(bf16x4*)(a.dst[s] + (size_t)off * 4) = r;
  }
}

// ---------------------------------------------------------------------------
// FAST GEMM (m97 structure): C[M,N] = A[M,K] @ W[N,K]^T, bf16 in, bf16/fp32 out.
// 128x128 tile, BK=32, global_load_lds width=16 staging, linear LDS.
// ---------------------------------------------------------------------------
template <typename CT>
__launch_bounds__(256, 3)
__global__ void gemm_lds(const short* __restrict__ A, const short* __restrict__ W,
                         CT* __restrict__ C, int M, int N, int K) {
  __shared__ short As[128 * 32];
  __shared__ short Ws[128 * 32];
  const int tid  = threadIdx.x;
  const int lane = tid & 63;
  const int w    = tid >> 6;
  const int wm = w >> 1, wn = w & 1;
  const int lr = lane & 15, lg = lane >> 4;
  const int m0 = blockIdx.y * 128, n0 = blockIdx.x * 128;

  const size_t a0 = (size_t)(m0 + w * 16 + (lane >> 2)) * K + (lane & 3) * 8;
  const size_t a1 = a0 + (size_t)64 * K;
  const size_t b0 = (size_t)(n0 + w * 16 + (lane >> 2)) * K + (lane & 3) * 8;
  const size_t b1 = b0 + (size_t)64 * K;
  short* lA0 = &As[(w * 16) * 32];
  short* lA1 = &As[(64 + w * 16) * 32];
  short* lB0 = &Ws[(w * 16) * 32];
  short* lB1 = &Ws[(64 + w * 16) * 32];

  f32x4 acc[4][4] = {};

  for (int k0 = 0; k0 < K; k0 += 32) {
    __syncthreads();
    gll16(A + a0 + k0, lA0);
    gll16(A + a1 + k0, lA1);
    gll16(W + b0 + k0, lB0);
    gll16(W + b1 + k0, lB1);
    __syncthreads();
    bf16x8 af[4], bfr[4];
#pragma unroll
    for (int i = 0; i < 4; ++i) {
      af[i]  = *(const bf16x8*)&As[(wm * 64 + i * 16 + lr) * 32 + lg * 8];
      bfr[i] = *(const bf16x8*)&Ws[(wn * 64 + i * 16 + lr) * 32 + lg * 8];
    }
#pragma unroll
    for (int i = 0; i < 4; ++i)
#pragma unroll
      for (int j = 0; j < 4; ++j)
        acc[i][j] = __builtin_amdgcn_mfma_f32_16x16x32_bf16(af[i], bfr[j], acc[i][j], 0, 0, 0);
  }

#pragma unroll
  for (int i = 0; i < 4; ++i)
#pragma unroll
    for (int j = 0; j < 4; ++j) {
      const int row = m0 + wm * 64 + i * 16 + lg * 4;
      const int col = n0 + wn * 64 + j * 16 + lr;
#pragma unroll
      for (int r = 0; r < 4; ++r)
        storeC(&C[(size_t)(row + r) * N + col], acc[i][j][r]);
    }
}

// ---------------------------------------------------------------------------
// FALLBACK GEMM (register-staged, converts fp32 in flight).
// ---------------------------------------------------------------------------
template <typename AT, typename CT>
__launch_bounds__(256, 2)
__global__ void gemm_bt(const AT* __restrict__ A, const float* __restrict__ W,
                        CT* __restrict__ C, int M, int N, int K) {
  __shared__ short As[128][40];
  __shared__ short Ws[128][40];
  const int tid  = threadIdx.x;
  const int lane = tid & 63;
  const int wid  = tid >> 6;
  const int wm = wid >> 1, wn = wid & 1;
  const int lr = lane & 15, lg = lane >> 4;
  const int m0 = blockIdx.y * 128, n0 = blockIdx.x * 128;
  const int srow = tid >> 2;
  const int scol = (tid & 3) * 8;

  f32x4 acc[4][4] = {};
  const AT*    Ap = A + (size_t)(m0 + srow) * K + scol;
  const float* Wp = W + (size_t)(n0 + srow) * K + scol;

  for (int k0 = 0; k0 < K; k0 += 32) {
    bf16x8 a0, a1, b0, b1;
    if constexpr (sizeof(AT) == 4) {
      a0 = cvt8(*(const f32x4*)(Ap + k0), *(const f32x4*)(Ap + k0 + 4));
      a1 = cvt8(*(const f32x4*)(Ap + (size_t)64 * K + k0),
                *(const f32x4*)(Ap + (size_t)64 * K + k0 + 4));
    } else {
      a0 = *(const bf16x8*)(Ap + k0);
      a1 = *(const bf16x8*)(Ap + (size_t)64 * K + k0);
    }
    b0 = cvt8(*(const f32x4*)(Wp + k0), *(const f32x4*)(Wp + k0 + 4));
    b1 = cvt8(*(const f32x4*)(Wp + (size_t)64 * K + k0),
              *(const f32x4*)(Wp + (size_t)64 * K + k0 + 4));
    __syncthreads();
    *(bf16x8*)&As[srow][scol]      = a0;
    *(bf16x8*)&As[srow + 64][scol] = a1;
    *(bf16x8*)&Ws[srow][scol]      = b0;
    *(bf16x8*)&Ws[srow + 64][scol] = b1;
    __syncthreads();
    bf16x8 af[4], bfr[4];
#pragma unroll
    for (int i = 0; i < 4; ++i) {
      af[i]  = *(const bf16x8*)&As[wm * 64 + i * 16 + lr][lg * 8];
      bfr[i] = *(const bf16x8*)&Ws[wn * 64 + i * 16 + lr][lg * 8];
    }
#pragma unroll
    for (int i = 0; i < 4; ++i)
#pragma unroll
      for (int j = 0; j < 4; ++j)
        acc[i][j] = __builtin_amdgcn_mfma_f32_16x16x32_bf16(af[i], bfr[j], acc[i][j], 0, 0, 0);
  }
#pragma unroll
  for (int i = 0; i < 4; ++i)
#pragma unroll
    for (int j = 0; j < 4; ++j) {
      const int row = m0 + wm * 64 + i * 16 + lg * 4;
      const int col = n0 + wn * 64 + j * 16 + lr;
#pragma unroll
      for (int r = 0; r < 4; ++r)
        storeC(&C[(size_t)(row + r) * N + col], acc[i][j][r]);
    }
}

// ---------------------------------------------------------------------------
// RoPE, head h -> cols 64h..64h+63 of a [rows, rowstride] bf16 buffer.
// NH=40 covers Q(32)+K(8) in the fused QKV buffer (V cols untouched).
// ---------------------------------------------------------------------------
template <int NH>
__global__ void rope_kernel(short* __restrict__ buf, int rowstride, int total) {
  int idx = blockIdx.x * 256 + threadIdx.x;
  if (idx >= total) return;
  const int i   = idx & 31;
  const int hh  = (idx >> 5) % NH;
  const int row = (idx >> 5) / NH;
  const int pos = row & (S_LEN - 1);
  const float invf = exp2f(-(float)i * (13.287712379549449f / 32.0f));
  const float ang  = (float)pos * invf;
  float sn, c;
  sincosf(ang, &sn, &c);
  size_t base = (size_t)row * rowstride + hh * 64;
  float x1 = bf2f(buf[base + i]);
  float x2 = bf2f(buf[base + i + 32]);
  buf[base + i]      = f2bf(x1 * c - x2 * sn);
  buf[base + i + 32] = f2bf(x2 * c + x1 * sn);
}

// ---------------------------------------------------------------------------
// Flash attention, double-swapped MFMA: lane's q = lane&15 for QK^T output,
// softmax, P-frag AND PV output -> softmax fully in-register.
// This round: K-frag register prefetch one tile ahead (T14), cvt_pk P-pack
// (T12), defer-max rescale skip (T13, THR=8 in exp2 domain).
// Grid (S/128, NH, B), 256 thr = 4 waves, wave owns 32 q-rows.
// ---------------------------------------------------------------------------
#define NT (S_LEN / 64)
__launch_bounds__(256, 2)
__global__ void attn_kernel(const short* __restrict__ Q, const short* __restrict__ K,
                            const short* __restrict__ V, short* __restrict__ O,
                            int qs, int ks_, int os) {
  const int qt = blockIdx.x, h = blockIdx.y, b = blockIdx.z;
  const int kv = h >> 2;
  const int tid  = threadIdx.x;
  const int lane = tid & 63, w = tid >> 6;
  const int lr = lane & 15, lg = lane >> 4;

  __shared__ short Vt[2][64][72];   // [buf][d][kc-permuted]

  const int q0 = qt * 128 + w * 32;
  bf16x8 qa[2][2];
#pragma unroll
  for (int fr = 0; fr < 2; ++fr) {
    const short* qp = Q + (size_t)(b * S_LEN + q0 + fr * 16 + lr) * qs + h * HEAD_DIM + lg * 8;
    qa[fr][0] = *(const bf16x8*)qp;
    qa[fr][1] = *(const bf16x8*)(qp + 32);
  }

  f32x4 o[2][4] = {};               // [fr][df], row=d_local, col=q=lr
  float mrow[2] = {-1e30f, -1e30f};
  float lrow[2] = {0.f, 0.f};

  // V staging: thread owns k-row (kt*64+lane), d-cols vdb..vdb+15.
  // column permutation c(k): bits c5=k5, c4c3=k3k2, c2=k4, c1c0=k1k0
  const int vdb   = w * 16;
  const int cperm = (lane & 32) + ((lane >> 2) & 3) * 8 + ((lane >> 4) & 1) * 4 + (lane & 3);
  const short* vbase = V + ((size_t)(b * S_LEN) + lane) * ks_ + kv * HEAD_DIM + vdb;
  bf16x8 vp0 = *(const bf16x8*)vbase;
  bf16x8 vp1 = *(const bf16x8*)(vbase + 8);

  // K A-frag prefetch registers (one tile ahead)
  const short* kbase = K + (size_t)(b * S_LEN + lr) * ks_ + kv * HEAD_DIM + lg * 8;
  bf16x8 kf[4][2];
#pragma unroll
  for (int nf = 0; nf < 4; ++nf) {
    kf[nf][0] = *(const bf16x8*)(kbase + (size_t)nf * 16 * ks_);
    kf[nf][1] = *(const bf16x8*)(kbase + (size_t)nf * 16 * ks_ + 32);
  }

  const float SC = 0.125f * 1.4426950408889634f;   // HD^-0.5 * log2(e)

  for (int kt = 0; kt < NT; ++kt) {
    const int cur = kt & 1;
    // ---- write staged V (transposed + column-permuted) ----
#pragma unroll
    for (int j = 0; j < 8; ++j) Vt[cur][vdb + j][cperm] = vp0[j];
#pragma unroll
    for (int j = 0; j < 8; ++j) Vt[cur][vdb + 8 + j][cperm] = vp1[j];
    __syncthreads();
    // ---- prefetch next V tile into regs ----
    if (kt + 1 < NT) {
      const short* vp = vbase + (size_t)(kt + 1) * 64 * ks_;
      vp0 = *(const bf16x8*)vp;
      vp1 = *(const bf16x8*)(vp + 8);
    }
    // ---- QK^T swapped: sf[fr][nf] row=k_local col=q ----
    f32x4 sf[2][4];
#pragma unroll
    for (int nf = 0; nf < 4; ++nf)
#pragma unroll
      for (int fr = 0; fr < 2; ++fr) {
        f32x4 t = {};
        t = __builtin_amdgcn_mfma_f32_16x16x32_bf16(kf[nf][0], qa[fr][0], t, 0, 0, 0);
        t = __builtin_amdgcn_mfma_f32_16x16x32_bf16(kf[nf][1], qa[fr][1], t, 0, 0, 0);
        sf[fr][nf] = t;
      }
    // ---- prefetch next K tile frags (regs free after mfma issue; loads
    //      covered by softmax+PV below) ----
    if (kt + 1 < NT) {
      const short* kp = kbase + (size_t)(kt + 1) * 64 * ks_;
#pragma unroll
      for (int nf = 0; nf < 4; ++nf) {
        kf[nf][0] = *(const bf16x8*)(kp + (size_t)nf * 16 * ks_);
        kf[nf][1] = *(const bf16x8*)(kp + (size_t)nf * 16 * ks_ + 32);
      }
    }
    // ---- in-register online softmax, defer-max (T13), cvt_pk pack (T12) ----
    bf16x8 pa[2][2];
#pragma unroll
    for (int fr = 0; fr < 2; ++fr) {
      float mx = -1e30f;
#pragma unroll
      for (int nf = 0; nf < 4; ++nf) {
        float m01 = fmaxf(sf[fr][nf][0], sf[fr][nf][1]);
        float m23 = fmaxf(sf[fr][nf][2], sf[fr][nf][3]);
        mx = fmaxf(mx, fmaxf(m01, m23));
      }
      mx = fmaxf(mx, __shfl_xor(mx, 16));
      mx = fmaxf(mx, __shfl_xor(mx, 32));
      // defer-max: only rescale when the max grew by > 8 (exp2 domain)
      if (!__all((mx - mrow[fr]) * SC <= 8.0f)) {
        const float mnew  = fmaxf(mrow[fr], mx);
        const float alpha = exp2f((mrow[fr] - mnew) * SC);
        mrow[fr] = mnew;
        lrow[fr] *= alpha;
#pragma unroll
        for (int df = 0; df < 4; ++df) o[fr][df] *= alpha;
      }
      const float mref = mrow[fr];
      float sum = 0.f;
#pragma unroll
      for (int nf = 0; nf < 4; ++nf)
#pragma unroll
        for (int r = 0; r < 4; ++r) {
          float pv = exp2f((sf[fr][nf][r] - mref) * SC);
          sf[fr][nf][r] = pv;
          sum += pv;
        }
      sum += __shfl_xor(sum, 16);
      sum += __shfl_xor(sum, 32);
      lrow[fr] += sum;
      // pack P into B-frag k-slot layout via v_cvt_pk_bf16_f32
#pragma unroll
      for (int ks2 = 0; ks2 < 2; ++ks2) {
        u32x4 pk;
        pk[0] = cvtpk(sf[fr][2 * ks2][0], sf[fr][2 * ks2][1]);
        pk[1] = cvtpk(sf[fr][2 * ks2][2], sf[fr][2 * ks2][3]);
        pk[2] = cvtpk(sf[fr][2 * ks2 + 1][0], sf[fr][2 * ks2 + 1][1]);
        pk[3] = cvtpk(sf[fr][2 * ks2 + 1][2], sf[fr][2 * ks2 + 1][3]);
        pa[fr][ks2] = __builtin_bit_cast(bf16x8, pk);
      }
    }
    // ---- PV swapped: o += mfma(V_frag, P_frag) ----
    __builtin_amdgcn_s_setprio(1);
#pragma unroll
    for (int ks2 = 0; ks2 < 2; ++ks2) {
      bf16x8 vb[4];
#pragma unroll
      for (int df = 0; df < 4; ++df)
        vb[df] = *(const bf16x8*)&Vt[cur][df * 16 + lr][ks2 * 32 + lg * 8];
#pragma unroll
      for (int fr = 0; fr < 2; ++fr)
#pragma unroll
        for (int df = 0; df < 4; ++df)
          o[fr][df] = __builtin_amdgcn_mfma_f32_16x16x32_bf16(vb[df], pa[fr][ks2], o[fr][df], 0, 0, 0);
    }
    __builtin_amdgcn_s_setprio(0);
  }

  // ---- epilogue: lane q = lr, d = df*16 + 4lg + r (8B packed store) ----
#pragma unroll
  for (int fr = 0; fr < 2; ++fr) {
    const float invl = 1.0f / lrow[fr];
    const size_t orow = (size_t)(b * S_LEN + q0 + fr * 16 + lr) * os + h * HEAD_DIM;
#pragma unroll
    for (int df = 0; df < 4; ++df) {
      u32x2 pk;
      pk[0] = cvtpk(o[fr][df][0] * invl, o[fr][df][1] * invl);
      pk[1] = cvtpk(o[fr][df][2] * invl, o[fr][df][3] * invl);
      *(u32x2*)&O[orow + df * 16 + 4 * lg] = pk;
    }
  }
}

// ---------------------------------------------------------------------------
extern "C" void kernel_launch(void* const* d_in, const int* in_sizes, int n_in,
                              void* d_out, int out_size, void* d_ws, size_t ws_size,
                              hipStream_t stream) {
  (void)in_sizes; (void)n_in; (void)out_size;
  const float* hidden = (const float*)d_in[0];
  const float* wq = (const float*)d_in[1];
  const float* wk = (const float*)d_in[2];
  const float* wv = (const float*)d_in[3];
  const float* wo = (const float*)d_in[4];
  float* out = (float*)d_out;

  const int M = 2 * S_LEN;                        // 4096
  const size_t nHid  = (size_t)M * HIDDEN;        // 8388608
  const size_t nW    = (size_t)HIDDEN * HIDDEN;   // 4194304
  const size_t nWkv  = (size_t)KVD * HIDDEN;      // 1048576
  const size_t nWcat = nW + 2 * nWkv;             // 6291456  (wq|wk|wv rows)
  const int    NQKV  = HIDDEN + 2 * KVD;          // 3072
  const size_t nQKV  = (size_t)M * NQKV;          // 12582912

  const size_t fastElems = nHid + nWcat + nW + nQKV + nHid;  // 39845888
  if (ws_size >= fastElems * sizeof(short)) {
    short* hb   = (short*)d_ws;
    short* wcat = hb + nHid;          // [3072][2048]: wq rows, wk rows, wv rows
    short* wob  = wcat + nWcat;
    short* QKV  = wob + nW;           // [4096][3072]: Q | K | V
    short* AO   = QKV + nQKV;

    CvtArgs ca;
    ca.src[0] = hidden; ca.dst[0] = hb;            ca.cnt4[0] = (int)(nHid / 4);
    ca.src[1] = wq;     ca.dst[1] = wcat;          ca.cnt4[1] = (int)(nW / 4);
    ca.src[2] = wk;     ca.dst[2] = wcat + nW;     ca.cnt4[2] = (int)(nWkv / 4);
    ca.src[3] = wv;     ca.dst[3] = wcat + nW + nWkv; ca.cnt4[3] = (int)(nWkv / 4);
    ca.src[4] = wo;     ca.dst[4] = wob;           ca.cnt4[4] = (int)(nW / 4);
    const int total4 = (int)((nHid + nWcat + nW) / 4);
    cvt_bf16<<<2048, 256, 0, stream>>>(ca, total4);

    // fused QKV projection: [4096,3072] = hb @ wcat^T
    gemm_lds<short><<<dim3(NQKV / 128, 32), 256, 0, stream>>>(hb, wcat, QKV, M, NQKV, HIDDEN);
    // fused RoPE over Q(32 heads) + K(8 heads) = cols 0..2559
    const int rtot = M * 40 * 32;
    rope_kernel<40><<<(rtot + 255) / 256, 256, 0, stream>>>(QKV, NQKV, rtot);
    // attention: Q at col 0, K at col 2048, V at col 2560 of QKV
    attn_kernel<<<dim3(S_LEN / 128, N_HEADS, 2), 256, 0, stream>>>(
        QKV, QKV + HIDDEN, QKV + HIDDEN + KVD, AO, NQKV, NQKV, HIDDEN);
    // output projection
    gemm_lds<float><<<dim3(16, 32), 256, 0, stream>>>(AO, wob, out, M, HIDDEN, HIDDEN);
  } else {
    short* Qb = (short*)d_ws;
    short* Kb = Qb + nHid;
    short* Vb = Kb + (size_t)M * KVD;
    short* AO = Vb + (size_t)M * KVD;
    gemm_bt<float, short><<<dim3(16, 32), 256, 0, stream>>>(hidden, wq, Qb, M, HIDDEN, HIDDEN);
    gemm_bt<float, short><<<dim3(4, 32), 256, 0, stream>>>(hidden, wk, Kb, M, KVD, HIDDEN);
    gemm_bt<float, short><<<dim3(4, 32), 256, 0, stream>>>(hidden, wv, Vb, M, KVD, HIDDEN);
    const int rq = M * N_HEADS * 32, rk = M * N_KV * 32;
    rope_kernel<N_HEADS><<<(rq + 255) / 256, 256, 0, stream>>>(Qb, HIDDEN, rq);
    rope_kernel<N_KV><<<(rk + 255) / 256, 256, 0, stream>>>(Kb, KVD, rk);
    attn_kernel<<<dim3(S_LEN / 128, N_HEADS, 2), 256, 0, stream>>>(
        Qb, Kb, Vb, AO, HIDDEN, KVD, HIDDEN);
    gemm_bt<short, float><<<dim3(16, 32), 256, 0, stream>>>(AO, wo, out, M, HIDDEN, HIDDEN);
  }
}

// Round 6
// 294.893 us; speedup vs baseline: 2.6171x; 1.0182x over previous
//
#include <hip/hip_runtime.h>
#include <stdint.h>

typedef __attribute__((ext_vector_type(8))) short bf16x8;
typedef __attribute__((ext_vector_type(4))) short bf16x4;
typedef __attribute__((ext_vector_type(4))) float f32x4;
typedef __attribute__((ext_vector_type(4))) unsigned u32x4;
typedef __attribute__((ext_vector_type(2))) unsigned u32x2;

#define S_LEN 2048
#define HIDDEN 2048
#define N_HEADS 32
#define N_KV 8
#define HEAD_DIM 64
#define KVD (N_KV * HEAD_DIM)   // 512

__device__ __forceinline__ float bf2f(short u) {
  return __builtin_bit_cast(float, ((unsigned)(unsigned short)u) << 16);
}
__device__ __forceinline__ short f2bf(float f) {
  unsigned u = __builtin_bit_cast(unsigned, f);
  u += 0x7FFFu + ((u >> 16) & 1u);
  return (short)(u >> 16);
}
__device__ __forceinline__ unsigned cvtpk(float lo, float hi) {
  unsigned r;
  asm("v_cvt_pk_bf16_f32 %0, %1, %2" : "=v"(r) : "v"(lo), "v"(hi));
  return r;
}
__device__ __forceinline__ bf16x8 cvt8(f32x4 lo, f32x4 hi) {
  bf16x8 r;
#pragma unroll
  for (int j = 0; j < 4; ++j) { r[j] = f2bf(lo[j]); r[j + 4] = f2bf(hi[j]); }
  return r;
}
__device__ __forceinline__ void storeC(float* p, float v) { *p = v; }
__device__ __forceinline__ void storeC(short* p, float v) { *p = f2bf(v); }

__device__ __forceinline__ void gll16(const void* g, void* l) {
  __builtin_amdgcn_global_load_lds(
      (const __attribute__((address_space(1))) void*)g,
      (__attribute__((address_space(3))) void*)l, 16, 0, 0);
}

// ---------------------------------------------------------------------------
// fp32 -> bf16 bulk convert, 5 segments, grid-stride, float4 units.
// ---------------------------------------------------------------------------
struct CvtArgs {
  const float* src[5];
  short* dst[5];
  int cnt4[5];
};
__global__ void cvt_bf16(CvtArgs a, int total4) {
  int u = blockIdx.x * 256 + threadIdx.x;
  const int stride = gridDim.x * 256;
  for (; u < total4; u += stride) {
    int s = 0, off = u;
    while (off >= a.cnt4[s]) { off -= a.cnt4[s]; ++s; }
    f32x4 v = *(const f32x4*)(a.src[s] + (size_t)off * 4);
    bf16x4 r;
#pragma unroll
    for (int j = 0; j < 4; ++j) r[j] = f2bf(v[j]);
    *(bf16x4*)(a.dst[s] + (size_t)off * 4) = r;
  }
}

// ---------------------------------------------------------------------------
// FAST GEMM (m97 structure): C[M,N] = A[M,K] @ W[N,K]^T, bf16 in, bf16/fp32 out.
// 128x128 tile, BK=32, global_load_lds width=16 staging, linear LDS.
// ---------------------------------------------------------------------------
template <typename CT>
__launch_bounds__(256, 3)
__global__ void gemm_lds(const short* __restrict__ A, const short* __restrict__ W,
                         CT* __restrict__ C, int M, int N, int K) {
  __shared__ short As[128 * 32];
  __shared__ short Ws[128 * 32];
  const int tid  = threadIdx.x;
  const int lane = tid & 63;
  const int w    = tid >> 6;
  const int wm = w >> 1, wn = w & 1;
  const int lr = lane & 15, lg = lane >> 4;
  const int m0 = blockIdx.y * 128, n0 = blockIdx.x * 128;

  const size_t a0 = (size_t)(m0 + w * 16 + (lane >> 2)) * K + (lane & 3) * 8;
  const size_t a1 = a0 + (size_t)64 * K;
  const size_t b0 = (size_t)(n0 + w * 16 + (lane >> 2)) * K + (lane & 3) * 8;
  const size_t b1 = b0 + (size_t)64 * K;
  short* lA0 = &As[(w * 16) * 32];
  short* lA1 = &As[(64 + w * 16) * 32];
  short* lB0 = &Ws[(w * 16) * 32];
  short* lB1 = &Ws[(64 + w * 16) * 32];

  f32x4 acc[4][4] = {};

  for (int k0 = 0; k0 < K; k0 += 32) {
    __syncthreads();
    gll16(A + a0 + k0, lA0);
    gll16(A + a1 + k0, lA1);
    gll16(W + b0 + k0, lB0);
    gll16(W + b1 + k0, lB1);
    __syncthreads();
    bf16x8 af[4], bfr[4];
#pragma unroll
    for (int i = 0; i < 4; ++i) {
      af[i]  = *(const bf16x8*)&As[(wm * 64 + i * 16 + lr) * 32 + lg * 8];
      bfr[i] = *(const bf16x8*)&Ws[(wn * 64 + i * 16 + lr) * 32 + lg * 8];
    }
#pragma unroll
    for (int i = 0; i < 4; ++i)
#pragma unroll
      for (int j = 0; j < 4; ++j)
        acc[i][j] = __builtin_amdgcn_mfma_f32_16x16x32_bf16(af[i], bfr[j], acc[i][j], 0, 0, 0);
  }

#pragma unroll
  for (int i = 0; i < 4; ++i)
#pragma unroll
    for (int j = 0; j < 4; ++j) {
      const int row = m0 + wm * 64 + i * 16 + lg * 4;
      const int col = n0 + wn * 64 + j * 16 + lr;
#pragma unroll
      for (int r = 0; r < 4; ++r)
        storeC(&C[(size_t)(row + r) * N + col], acc[i][j][r]);
    }
}

// ---------------------------------------------------------------------------
// FALLBACK GEMM (register-staged, converts fp32 in flight).
// ---------------------------------------------------------------------------
template <typename AT, typename CT>
__launch_bounds__(256, 2)
__global__ void gemm_bt(const AT* __restrict__ A, const float* __restrict__ W,
                        CT* __restrict__ C, int M, int N, int K) {
  __shared__ short As[128][40];
  __shared__ short Ws[128][40];
  const int tid  = threadIdx.x;
  const int lane = tid & 63;
  const int wid  = tid >> 6;
  const int wm = wid >> 1, wn = wid & 1;
  const int lr = lane & 15, lg = lane >> 4;
  const int m0 = blockIdx.y * 128, n0 = blockIdx.x * 128;
  const int srow = tid >> 2;
  const int scol = (tid & 3) * 8;

  f32x4 acc[4][4] = {};
  const AT*    Ap = A + (size_t)(m0 + srow) * K + scol;
  const float* Wp = W + (size_t)(n0 + srow) * K + scol;

  for (int k0 = 0; k0 < K; k0 += 32) {
    bf16x8 a0, a1, b0, b1;
    if constexpr (sizeof(AT) == 4) {
      a0 = cvt8(*(const f32x4*)(Ap + k0), *(const f32x4*)(Ap + k0 + 4));
      a1 = cvt8(*(const f32x4*)(Ap + (size_t)64 * K + k0),
                *(const f32x4*)(Ap + (size_t)64 * K + k0 + 4));
    } else {
      a0 = *(const bf16x8*)(Ap + k0);
      a1 = *(const bf16x8*)(Ap + (size_t)64 * K + k0);
    }
    b0 = cvt8(*(const f32x4*)(Wp + k0), *(const f32x4*)(Wp + k0 + 4));
    b1 = cvt8(*(const f32x4*)(Wp + (size_t)64 * K + k0),
              *(const f32x4*)(Wp + (size_t)64 * K + k0 + 4));
    __syncthreads();
    *(bf16x8*)&As[srow][scol]      = a0;
    *(bf16x8*)&As[srow + 64][scol] = a1;
    *(bf16x8*)&Ws[srow][scol]      = b0;
    *(bf16x8*)&Ws[srow + 64][scol] = b1;
    __syncthreads();
    bf16x8 af[4], bfr[4];
#pragma unroll
    for (int i = 0; i < 4; ++i) {
      af[i]  = *(const bf16x8*)&As[wm * 64 + i * 16 + lr][lg * 8];
      bfr[i] = *(const bf16x8*)&Ws[wn * 64 + i * 16 + lr][lg * 8];
    }
#pragma unroll
    for (int i = 0; i < 4; ++i)
#pragma unroll
      for (int j = 0; j < 4; ++j)
        acc[i][j] = __builtin_amdgcn_mfma_f32_16x16x32_bf16(af[i], bfr[j], acc[i][j], 0, 0, 0);
  }
#pragma unroll
  for (int i = 0; i < 4; ++i)
#pragma unroll
    for (int j = 0; j < 4; ++j) {
      const int row = m0 + wm * 64 + i * 16 + lg * 4;
      const int col = n0 + wn * 64 + j * 16 + lr;
#pragma unroll
      for (int r = 0; r < 4; ++r)
        storeC(&C[(size_t)(row + r) * N + col], acc[i][j][r]);
    }
}

// ---------------------------------------------------------------------------
// RoPE, head h -> cols 64h..64h+63 of a [rows, rowstride] bf16 buffer.
// ---------------------------------------------------------------------------
template <int NH>
__global__ void rope_kernel(short* __restrict__ buf, int rowstride, int total) {
  int idx = blockIdx.x * 256 + threadIdx.x;
  if (idx >= total) return;
  const int i   = idx & 31;
  const int hh  = (idx >> 5) % NH;
  const int row = (idx >> 5) / NH;
  const int pos = row & (S_LEN - 1);
  const float invf = exp2f(-(float)i * (13.287712379549449f / 32.0f));
  const float ang  = (float)pos * invf;
  float sn, c;
  sincosf(ang, &sn, &c);
  size_t base = (size_t)row * rowstride + hh * 64;
  float x1 = bf2f(buf[base + i]);
  float x2 = bf2f(buf[base + i + 32]);
  buf[base + i]      = f2bf(x1 * c - x2 * sn);
  buf[base + i + 32] = f2bf(x2 * c + x1 * sn);
}

// ---------------------------------------------------------------------------
// Flash attention, double-swapped MFMA; this round the softmax common path
// has ZERO cross-lane ops:
//  - speculative defer-max: lane-local max + __all() test; shuffle-reduce
//    and o/lsum rescale only on the (rare) wave-uniform failure path
//  - lane-local partial l-sums, combined once in the epilogue
// Grid (S/128, NH, B), 256 thr = 4 waves, wave owns 32 q-rows.
// ---------------------------------------------------------------------------
#define NT (S_LEN / 64)
__launch_bounds__(256, 2)
__global__ void attn_kernel(const short* __restrict__ Q, const short* __restrict__ K,
                            const short* __restrict__ V, short* __restrict__ O,
                            int qs, int ks_, int os) {
  const int qt = blockIdx.x, h = blockIdx.y, b = blockIdx.z;
  const int kv = h >> 2;
  const int tid  = threadIdx.x;
  const int lane = tid & 63, w = tid >> 6;
  const int lr = lane & 15, lg = lane >> 4;

  __shared__ short Vt[2][64][72];   // [buf][d][kc-permuted]

  const int q0 = qt * 128 + w * 32;
  bf16x8 qa[2][2];
#pragma unroll
  for (int fr = 0; fr < 2; ++fr) {
    const short* qp = Q + (size_t)(b * S_LEN + q0 + fr * 16 + lr) * qs + h * HEAD_DIM + lg * 8;
    qa[fr][0] = *(const bf16x8*)qp;
    qa[fr][1] = *(const bf16x8*)(qp + 32);
  }

  f32x4 o[2][4] = {};               // [fr][df], row=d_local, col=q=lr
  float mrow[2] = {-1e30f, -1e30f}; // wave-uniform running max (raw domain)
  float msc[2]  = {-1e30f, -1e30f}; // mrow * SC
  float lsum[2] = {0.f, 0.f};       // LANE-LOCAL partial denominators

  // V staging: thread owns k-row (kt*64+lane), d-cols vdb..vdb+15.
  // column permutation c(k): bits c5=k5, c4c3=k3k2, c2=k4, c1c0=k1k0
  const int vdb   = w * 16;
  const int cperm = (lane & 32) + ((lane >> 2) & 3) * 8 + ((lane >> 4) & 1) * 4 + (lane & 3);
  const short* vbase = V + ((size_t)(b * S_LEN) + lane) * ks_ + kv * HEAD_DIM + vdb;
  bf16x8 vp0 = *(const bf16x8*)vbase;
  bf16x8 vp1 = *(const bf16x8*)(vbase + 8);

  // K A-frag prefetch registers (one tile ahead)
  const short* kbase = K + (size_t)(b * S_LEN + lr) * ks_ + kv * HEAD_DIM + lg * 8;
  bf16x8 kf[4][2];
#pragma unroll
  for (int nf = 0; nf < 4; ++nf) {
    kf[nf][0] = *(const bf16x8*)(kbase + (size_t)nf * 16 * ks_);
    kf[nf][1] = *(const bf16x8*)(kbase + (size_t)nf * 16 * ks_ + 32);
  }

  const float SC   = 0.125f * 1.4426950408889634f;   // HD^-0.5 * log2(e)
  const float THRR = 8.0f / SC;                      // defer threshold, raw domain

  for (int kt = 0; kt < NT; ++kt) {
    const int cur = kt & 1;
    // ---- write staged V (transposed + column-permuted) ----
#pragma unroll
    for (int j = 0; j < 8; ++j) Vt[cur][vdb + j][cperm] = vp0[j];
#pragma unroll
    for (int j = 0; j < 8; ++j) Vt[cur][vdb + 8 + j][cperm] = vp1[j];
    __syncthreads();
    // ---- prefetch next V tile into regs ----
    if (kt + 1 < NT) {
      const short* vp = vbase + (size_t)(kt + 1) * 64 * ks_;
      vp0 = *(const bf16x8*)vp;
      vp1 = *(const bf16x8*)(vp + 8);
    }
    // ---- QK^T swapped: sf[fr][nf] row=k_local col=q ----
    f32x4 sf[2][4];
    __builtin_amdgcn_s_setprio(1);
#pragma unroll
    for (int nf = 0; nf < 4; ++nf)
#pragma unroll
      for (int fr = 0; fr < 2; ++fr) {
        f32x4 t = {};
        t = __builtin_amdgcn_mfma_f32_16x16x32_bf16(kf[nf][0], qa[fr][0], t, 0, 0, 0);
        t = __builtin_amdgcn_mfma_f32_16x16x32_bf16(kf[nf][1], qa[fr][1], t, 0, 0, 0);
        sf[fr][nf] = t;
      }
    __builtin_amdgcn_s_setprio(0);
    // ---- prefetch next K tile frags (covered by softmax+PV) ----
    if (kt + 1 < NT) {
      const short* kp = kbase + (size_t)(kt + 1) * 64 * ks_;
#pragma unroll
      for (int nf = 0; nf < 4; ++nf) {
        kf[nf][0] = *(const bf16x8*)(kp + (size_t)nf * 16 * ks_);
        kf[nf][1] = *(const bf16x8*)(kp + (size_t)nf * 16 * ks_ + 32);
      }
    }
    // ---- softmax: zero cross-lane ops in common path ----
    bf16x8 pa[2][2];
#pragma unroll
    for (int fr = 0; fr < 2; ++fr) {
      float lmax = fmaxf(fmaxf(sf[fr][0][0], sf[fr][0][1]), fmaxf(sf[fr][0][2], sf[fr][0][3]));
#pragma unroll
      for (int nf = 1; nf < 4; ++nf) {
        float m01 = fmaxf(sf[fr][nf][0], sf[fr][nf][1]);
        float m23 = fmaxf(sf[fr][nf][2], sf[fr][nf][3]);
        lmax = fmaxf(lmax, fmaxf(m01, m23));
      }
      // speculative defer-max: rare path only when lane-local max grew past thr
      if (!__all(lmax <= mrow[fr] + THRR)) {
        float mx = fmaxf(lmax, __shfl_xor(lmax, 16));
        mx = fmaxf(mx, __shfl_xor(mx, 32));
        const float mnew  = fmaxf(mrow[fr], mx);
        const float alpha = exp2f((mrow[fr] - mnew) * SC);
        mrow[fr] = mnew;
        msc[fr]  = mnew * SC;
        lsum[fr] *= alpha;
#pragma unroll
        for (int df = 0; df < 4; ++df) o[fr][df] *= alpha;
      }
      const float nm = msc[fr];
      float s = 0.f;
#pragma unroll
      for (int nf = 0; nf < 4; ++nf)
#pragma unroll
        for (int r = 0; r < 4; ++r) {
          float pv = exp2f(fmaf(sf[fr][nf][r], SC, -nm));
          sf[fr][nf][r] = pv;
          s += pv;
        }
      lsum[fr] += s;
      // pack P into B-frag k-slot layout via v_cvt_pk_bf16_f32
#pragma unroll
      for (int ks2 = 0; ks2 < 2; ++ks2) {
        u32x4 pk;
        pk[0] = cvtpk(sf[fr][2 * ks2][0], sf[fr][2 * ks2][1]);
        pk[1] = cvtpk(sf[fr][2 * ks2][2], sf[fr][2 * ks2][3]);
        pk[2] = cvtpk(sf[fr][2 * ks2 + 1][0], sf[fr][2 * ks2 + 1][1]);
        pk[3] = cvtpk(sf[fr][2 * ks2 + 1][2], sf[fr][2 * ks2 + 1][3]);
        pa[fr][ks2] = __builtin_bit_cast(bf16x8, pk);
      }
    }
    // ---- PV swapped: o += mfma(V_frag, P_frag) ----
    __builtin_amdgcn_s_setprio(1);
#pragma unroll
    for (int ks2 = 0; ks2 < 2; ++ks2) {
      bf16x8 vb[4];
#pragma unroll
      for (int df = 0; df < 4; ++df)
        vb[df] = *(const bf16x8*)&Vt[cur][df * 16 + lr][ks2 * 32 + lg * 8];
#pragma unroll
      for (int fr = 0; fr < 2; ++fr)
#pragma unroll
        for (int df = 0; df < 4; ++df)
          o[fr][df] = __builtin_amdgcn_mfma_f32_16x16x32_bf16(vb[df], pa[fr][ks2], o[fr][df], 0, 0, 0);
    }
    __builtin_amdgcn_s_setprio(0);
  }

  // ---- epilogue: combine lane-partial denominators once, then store ----
#pragma unroll
  for (int fr = 0; fr < 2; ++fr) {
    float ls = lsum[fr];
    ls += __shfl_xor(ls, 16);
    ls += __shfl_xor(ls, 32);
    const float invl = 1.0f / ls;
    const size_t orow = (size_t)(b * S_LEN + q0 + fr * 16 + lr) * os + h * HEAD_DIM;
#pragma unroll
    for (int df = 0; df < 4; ++df) {
      u32x2 pk;
      pk[0] = cvtpk(o[fr][df][0] * invl, o[fr][df][1] * invl);
      pk[1] = cvtpk(o[fr][df][2] * invl, o[fr][df][3] * invl);
      *(u32x2*)&O[orow + df * 16 + 4 * lg] = pk;
    }
  }
}

// ---------------------------------------------------------------------------
extern "C" void kernel_launch(void* const* d_in, const int* in_sizes, int n_in,
                              void* d_out, int out_size, void* d_ws, size_t ws_size,
                              hipStream_t stream) {
  (void)in_sizes; (void)n_in; (void)out_size;
  const float* hidden = (const float*)d_in[0];
  const float* wq = (const float*)d_in[1];
  const float* wk = (const float*)d_in[2];
  const float* wv = (const float*)d_in[3];
  const float* wo = (const float*)d_in[4];
  float* out = (float*)d_out;

  const int M = 2 * S_LEN;                        // 4096
  const size_t nHid  = (size_t)M * HIDDEN;        // 8388608
  const size_t nW    = (size_t)HIDDEN * HIDDEN;   // 4194304
  const size_t nWkv  = (size_t)KVD * HIDDEN;      // 1048576
  const size_t nWcat = nW + 2 * nWkv;             // 6291456  (wq|wk|wv rows)
  const int    NQKV  = HIDDEN + 2 * KVD;          // 3072
  const size_t nQKV  = (size_t)M * NQKV;          // 12582912

  const size_t fastElems = nHid + nWcat + nW + nQKV + nHid;  // 39845888
  if (ws_size >= fastElems * sizeof(short)) {
    short* hb   = (short*)d_ws;
    short* wcat = hb + nHid;          // [3072][2048]: wq rows, wk rows, wv rows
    short* wob  = wcat + nWcat;
    short* QKV  = wob + nW;           // [4096][3072]: Q | K | V
    short* AO   = QKV + nQKV;

    CvtArgs ca;
    ca.src[0] = hidden; ca.dst[0] = hb;            ca.cnt4[0] = (int)(nHid / 4);
    ca.src[1] = wq;     ca.dst[1] = wcat;          ca.cnt4[1] = (int)(nW / 4);
    ca.src[2] = wk;     ca.dst[2] = wcat + nW;     ca.cnt4[2] = (int)(nWkv / 4);
    ca.src[3] = wv;     ca.dst[3] = wcat + nW + nWkv; ca.cnt4[3] = (int)(nWkv / 4);
    ca.src[4] = wo;     ca.dst[4] = wob;           ca.cnt4[4] = (int)(nW / 4);
    const int total4 = (int)((nHid + nWcat + nW) / 4);
    cvt_bf16<<<2048, 256, 0, stream>>>(ca, total4);

    // fused QKV projection: [4096,3072] = hb @ wcat^T
    gemm_lds<short><<<dim3(NQKV / 128, 32), 256, 0, stream>>>(hb, wcat, QKV, M, NQKV, HIDDEN);
    // fused RoPE over Q(32 heads) + K(8 heads) = cols 0..2559
    const int rtot = M * 40 * 32;
    rope_kernel<40><<<(rtot + 255) / 256, 256, 0, stream>>>(QKV, NQKV, rtot);
    // attention: Q at col 0, K at col 2048, V at col 2560 of QKV
    attn_kernel<<<dim3(S_LEN / 128, N_HEADS, 2), 256, 0, stream>>>(
        QKV, QKV + HIDDEN, QKV + HIDDEN + KVD, AO, NQKV, NQKV, HIDDEN);
    // output projection
    gemm_lds<float><<<dim3(16, 32), 256, 0, stream>>>(AO, wob, out, M, HIDDEN, HIDDEN);
  } else {
    short* Qb = (short*)d_ws;
    short* Kb = Qb + nHid;
    short* Vb = Kb + (size_t)M * KVD;
    short* AO = Vb + (size_t)M * KVD;
    gemm_bt<float, short><<<dim3(16, 32), 256, 0, stream>>>(hidden, wq, Qb, M, HIDDEN, HIDDEN);
    gemm_bt<float, short><<<dim3(4, 32), 256, 0, stream>>>(hidden, wk, Kb, M, KVD, HIDDEN);
    gemm_bt<float, short><<<dim3(4, 32), 256, 0, stream>>>(hidden, wv, Vb, M, KVD, HIDDEN);
    const int rq = M * N_HEADS * 32, rk = M * N_KV * 32;
    rope_kernel<N_HEADS><<<(rq + 255) / 256, 256, 0, stream>>>(Qb, HIDDEN, rq);
    rope_kernel<N_KV><<<(rk + 255) / 256, 256, 0, stream>>>(Kb, KVD, rk);
    attn_kernel<<<dim3(S_LEN / 128, N_HEADS, 2), 256, 0, stream>>>(
        Qb, Kb, Vb, AO, HIDDEN, KVD, HIDDEN);
    gemm_bt<short, float><<<dim3(16, 32), 256, 0, stream>>>(AO, wo, out, M, HIDDEN, HIDDEN);
  }
}

// Round 7
// 293.012 us; speedup vs baseline: 2.6339x; 1.0064x over previous
//
#include <hip/hip_runtime.h>
#include <stdint.h>

typedef __attribute__((ext_vector_type(8))) short bf16x8;
typedef __attribute__((ext_vector_type(4))) short bf16x4;
typedef __attribute__((ext_vector_type(4))) float f32x4;
typedef __attribute__((ext_vector_type(4))) unsigned u32x4;
typedef __attribute__((ext_vector_type(2))) unsigned u32x2;

#define S_LEN 2048
#define HIDDEN 2048
#define N_HEADS 32
#define N_KV 8
#define HEAD_DIM 64
#define KVD (N_KV * HEAD_DIM)   // 512

__device__ __forceinline__ float bf2f(short u) {
  return __builtin_bit_cast(float, ((unsigned)(unsigned short)u) << 16);
}
__device__ __forceinline__ short f2bf(float f) {
  unsigned u = __builtin_bit_cast(unsigned, f);
  u += 0x7FFFu + ((u >> 16) & 1u);
  return (short)(u >> 16);
}
__device__ __forceinline__ unsigned cvtpk(float lo, float hi) {
  unsigned r;
  asm("v_cvt_pk_bf16_f32 %0, %1, %2" : "=v"(r) : "v"(lo), "v"(hi));
  return r;
}
__device__ __forceinline__ bf16x8 cvt8(f32x4 lo, f32x4 hi) {
  bf16x8 r;
#pragma unroll
  for (int j = 0; j < 4; ++j) { r[j] = f2bf(lo[j]); r[j + 4] = f2bf(hi[j]); }
  return r;
}
__device__ __forceinline__ void storeC(float* p, float v) { *p = v; }
__device__ __forceinline__ void storeC(short* p, float v) { *p = f2bf(v); }

__device__ __forceinline__ void gll16(const void* g, void* l) {
  __builtin_amdgcn_global_load_lds(
      (const __attribute__((address_space(1))) void*)g,
      (__attribute__((address_space(3))) void*)l, 16, 0, 0);
}

// ---------------------------------------------------------------------------
// fp32 -> bf16 bulk convert, 5 segments, grid-stride, float4 units.
// ---------------------------------------------------------------------------
struct CvtArgs {
  const float* src[5];
  short* dst[5];
  int cnt4[5];
};
__global__ void cvt_bf16(CvtArgs a, int total4) {
  int u = blockIdx.x * 256 + threadIdx.x;
  const int stride = gridDim.x * 256;
  for (; u < total4; u += stride) {
    int s = 0, off = u;
    while (off >= a.cnt4[s]) { off -= a.cnt4[s]; ++s; }
    f32x4 v = *(const f32x4*)(a.src[s] + (size_t)off * 4);
    bf16x4 r;
#pragma unroll
    for (int j = 0; j < 4; ++j) r[j] = f2bf(v[j]);
    *(bf16x4*)(a.dst[s] + (size_t)off * 4) = r;
  }
}

// ---------------------------------------------------------------------------
// FAST GEMM (m97 structure): C[M,N] = A[M,K] @ W[N,K]^T, bf16 in, bf16/fp32 out.
// 128x128 tile, BK=32, global_load_lds width=16 staging, linear LDS.
// XCD-aware bijective block swizzle (T1) when nwg % 8 == 0.
// ---------------------------------------------------------------------------
template <typename CT>
__launch_bounds__(256, 3)
__global__ void gemm_lds(const short* __restrict__ A, const short* __restrict__ W,
                         CT* __restrict__ C, int M, int N, int K) {
  __shared__ short As[128 * 32];
  __shared__ short Ws[128 * 32];
  const int tid  = threadIdx.x;
  const int lane = tid & 63;
  const int w    = tid >> 6;
  const int wm = w >> 1, wn = w & 1;
  const int lr = lane & 15, lg = lane >> 4;

  int bx = blockIdx.x, by = blockIdx.y;
  {
    const int nwg = gridDim.x * gridDim.y;
    if ((nwg & 7) == 0) {
      const int bid = by * gridDim.x + bx;
      const int id2 = (bid & 7) * (nwg >> 3) + (bid >> 3);
      bx = id2 % gridDim.x;
      by = id2 / gridDim.x;
    }
  }
  const int m0 = by * 128, n0 = bx * 128;

  const size_t a0 = (size_t)(m0 + w * 16 + (lane >> 2)) * K + (lane & 3) * 8;
  const size_t a1 = a0 + (size_t)64 * K;
  const size_t b0 = (size_t)(n0 + w * 16 + (lane >> 2)) * K + (lane & 3) * 8;
  const size_t b1 = b0 + (size_t)64 * K;
  short* lA0 = &As[(w * 16) * 32];
  short* lA1 = &As[(64 + w * 16) * 32];
  short* lB0 = &Ws[(w * 16) * 32];
  short* lB1 = &Ws[(64 + w * 16) * 32];

  f32x4 acc[4][4] = {};

  for (int k0 = 0; k0 < K; k0 += 32) {
    __syncthreads();
    gll16(A + a0 + k0, lA0);
    gll16(A + a1 + k0, lA1);
    gll16(W + b0 + k0, lB0);
    gll16(W + b1 + k0, lB1);
    __syncthreads();
    bf16x8 af[4], bfr[4];
#pragma unroll
    for (int i = 0; i < 4; ++i) {
      af[i]  = *(const bf16x8*)&As[(wm * 64 + i * 16 + lr) * 32 + lg * 8];
      bfr[i] = *(const bf16x8*)&Ws[(wn * 64 + i * 16 + lr) * 32 + lg * 8];
    }
#pragma unroll
    for (int i = 0; i < 4; ++i)
#pragma unroll
      for (int j = 0; j < 4; ++j)
        acc[i][j] = __builtin_amdgcn_mfma_f32_16x16x32_bf16(af[i], bfr[j], acc[i][j], 0, 0, 0);
  }

#pragma unroll
  for (int i = 0; i < 4; ++i)
#pragma unroll
    for (int j = 0; j < 4; ++j) {
      const int row = m0 + wm * 64 + i * 16 + lg * 4;
      const int col = n0 + wn * 64 + j * 16 + lr;
#pragma unroll
      for (int r = 0; r < 4; ++r)
        storeC(&C[(size_t)(row + r) * N + col], acc[i][j][r]);
    }
}

// ---------------------------------------------------------------------------
// FALLBACK GEMM (register-staged, converts fp32 in flight).
// ---------------------------------------------------------------------------
template <typename AT, typename CT>
__launch_bounds__(256, 2)
__global__ void gemm_bt(const AT* __restrict__ A, const float* __restrict__ W,
                        CT* __restrict__ C, int M, int N, int K) {
  __shared__ short As[128][40];
  __shared__ short Ws[128][40];
  const int tid  = threadIdx.x;
  const int lane = tid & 63;
  const int wid  = tid >> 6;
  const int wm = wid >> 1, wn = wid & 1;
  const int lr = lane & 15, lg = lane >> 4;
  const int m0 = blockIdx.y * 128, n0 = blockIdx.x * 128;
  const int srow = tid >> 2;
  const int scol = (tid & 3) * 8;

  f32x4 acc[4][4] = {};
  const AT*    Ap = A + (size_t)(m0 + srow) * K + scol;
  const float* Wp = W + (size_t)(n0 + srow) * K + scol;

  for (int k0 = 0; k0 < K; k0 += 32) {
    bf16x8 a0, a1, b0, b1;
    if constexpr (sizeof(AT) == 4) {
      a0 = cvt8(*(const f32x4*)(Ap + k0), *(const f32x4*)(Ap + k0 + 4));
      a1 = cvt8(*(const f32x4*)(Ap + (size_t)64 * K + k0),
                *(const f32x4*)(Ap + (size_t)64 * K + k0 + 4));
    } else {
      a0 = *(const bf16x8*)(Ap + k0);
      a1 = *(const bf16x8*)(Ap + (size_t)64 * K + k0);
    }
    b0 = cvt8(*(const f32x4*)(Wp + k0), *(const f32x4*)(Wp + k0 + 4));
    b1 = cvt8(*(const f32x4*)(Wp + (size_t)64 * K + k0),
              *(const f32x4*)(Wp + (size_t)64 * K + k0 + 4));
    __syncthreads();
    *(bf16x8*)&As[srow][scol]      = a0;
    *(bf16x8*)&As[srow + 64][scol] = a1;
    *(bf16x8*)&Ws[srow][scol]      = b0;
    *(bf16x8*)&Ws[srow + 64][scol] = b1;
    __syncthreads();
    bf16x8 af[4], bfr[4];
#pragma unroll
    for (int i = 0; i < 4; ++i) {
      af[i]  = *(const bf16x8*)&As[wm * 64 + i * 16 + lr][lg * 8];
      bfr[i] = *(const bf16x8*)&Ws[wn * 64 + i * 16 + lr][lg * 8];
    }
#pragma unroll
    for (int i = 0; i < 4; ++i)
#pragma unroll
      for (int j = 0; j < 4; ++j)
        acc[i][j] = __builtin_amdgcn_mfma_f32_16x16x32_bf16(af[i], bfr[j], acc[i][j], 0, 0, 0);
  }
#pragma unroll
  for (int i = 0; i < 4; ++i)
#pragma unroll
    for (int j = 0; j < 4; ++j) {
      const int row = m0 + wm * 64 + i * 16 + lg * 4;
      const int col = n0 + wn * 64 + j * 16 + lr;
#pragma unroll
      for (int r = 0; r < 4; ++r)
        storeC(&C[(size_t)(row + r) * N + col], acc[i][j][r]);
    }
}

// ---------------------------------------------------------------------------
// RoPE, head h -> cols 64h..64h+63 of a [rows, rowstride] bf16 buffer.
// ---------------------------------------------------------------------------
template <int NH>
__global__ void rope_kernel(short* __restrict__ buf, int rowstride, int total) {
  int idx = blockIdx.x * 256 + threadIdx.x;
  if (idx >= total) return;
  const int i   = idx & 31;
  const int hh  = (idx >> 5) % NH;
  const int row = (idx >> 5) / NH;
  const int pos = row & (S_LEN - 1);
  const float invf = exp2f(-(float)i * (13.287712379549449f / 32.0f));
  const float ang  = (float)pos * invf;
  float sn, c;
  sincosf(ang, &sn, &c);
  size_t base = (size_t)row * rowstride + hh * 64;
  float x1 = bf2f(buf[base + i]);
  float x2 = bf2f(buf[base + i + 32]);
  buf[base + i]      = f2bf(x1 * c - x2 * sn);
  buf[base + i + 32] = f2bf(x2 * c + x1 * sn);
}

// ---------------------------------------------------------------------------
// Flash attention helpers (double-swapped MFMA layout).
// ---------------------------------------------------------------------------
__device__ __forceinline__ void qkt_mfma(const bf16x8 (&kf)[4][2],
                                         const bf16x8 (&qa)[2][2],
                                         f32x4 (&sf)[2][4]) {
  __builtin_amdgcn_s_setprio(1);
#pragma unroll
  for (int nf = 0; nf < 4; ++nf)
#pragma unroll
    for (int fr = 0; fr < 2; ++fr) {
      f32x4 t = {};
      t = __builtin_amdgcn_mfma_f32_16x16x32_bf16(kf[nf][0], qa[fr][0], t, 0, 0, 0);
      t = __builtin_amdgcn_mfma_f32_16x16x32_bf16(kf[nf][1], qa[fr][1], t, 0, 0, 0);
      sf[fr][nf] = t;
    }
  __builtin_amdgcn_s_setprio(0);
}

__device__ __forceinline__ void load_kf(bf16x8 (&kf)[4][2], const short* kbase,
                                        int t, int ks_) {
  const short* kp = kbase + (size_t)t * 64 * ks_;
#pragma unroll
  for (int nf = 0; nf < 4; ++nf) {
    kf[nf][0] = *(const bf16x8*)(kp + (size_t)nf * 16 * ks_);
    kf[nf][1] = *(const bf16x8*)(kp + (size_t)nf * 16 * ks_ + 32);
  }
}

__device__ __forceinline__ void softmax_pv(
    f32x4 (&sf)[2][4], const short (*vt)[72], f32x4 (&o)[2][4],
    float (&mrow)[2], float (&msc)[2], float (&lsum)[2],
    int lr, int lg, float SC, float THRR) {
  bf16x8 pa[2][2];
#pragma unroll
  for (int fr = 0; fr < 2; ++fr) {
    float lmax = fmaxf(fmaxf(sf[fr][0][0], sf[fr][0][1]), fmaxf(sf[fr][0][2], sf[fr][0][3]));
#pragma unroll
    for (int nf = 1; nf < 4; ++nf) {
      float m01 = fmaxf(sf[fr][nf][0], sf[fr][nf][1]);
      float m23 = fmaxf(sf[fr][nf][2], sf[fr][nf][3]);
      lmax = fmaxf(lmax, fmaxf(m01, m23));
    }
    // speculative defer-max: rare path only when lane-local max grew past thr
    if (!__all(lmax <= mrow[fr] + THRR)) {
      float mx = fmaxf(lmax, __shfl_xor(lmax, 16));
      mx = fmaxf(mx, __shfl_xor(mx, 32));
      const float mnew  = fmaxf(mrow[fr], mx);
      const float alpha = exp2f((mrow[fr] - mnew) * SC);
      mrow[fr] = mnew;
      msc[fr]  = mnew * SC;
      lsum[fr] *= alpha;
#pragma unroll
      for (int df = 0; df < 4; ++df) o[fr][df] *= alpha;
    }
    const float nm = msc[fr];
    float s = 0.f;
#pragma unroll
    for (int nf = 0; nf < 4; ++nf)
#pragma unroll
      for (int r = 0; r < 4; ++r) {
        float pv = exp2f(fmaf(sf[fr][nf][r], SC, -nm));
        sf[fr][nf][r] = pv;
        s += pv;
      }
    lsum[fr] += s;
#pragma unroll
    for (int ks2 = 0; ks2 < 2; ++ks2) {
      u32x4 pk;
      pk[0] = cvtpk(sf[fr][2 * ks2][0], sf[fr][2 * ks2][1]);
      pk[1] = cvtpk(sf[fr][2 * ks2][2], sf[fr][2 * ks2][3]);
      pk[2] = cvtpk(sf[fr][2 * ks2 + 1][0], sf[fr][2 * ks2 + 1][1]);
      pk[3] = cvtpk(sf[fr][2 * ks2 + 1][2], sf[fr][2 * ks2 + 1][3]);
      pa[fr][ks2] = __builtin_bit_cast(bf16x8, pk);
    }
  }
  __builtin_amdgcn_s_setprio(1);
#pragma unroll
  for (int ks2 = 0; ks2 < 2; ++ks2) {
    bf16x8 vb[4];
#pragma unroll
    for (int df = 0; df < 4; ++df)
      vb[df] = *(const bf16x8*)&vt[df * 16 + lr][ks2 * 32 + lg * 8];
#pragma unroll
    for (int fr = 0; fr < 2; ++fr)
#pragma unroll
      for (int df = 0; df < 4; ++df)
        o[fr][df] = __builtin_amdgcn_mfma_f32_16x16x32_bf16(vb[df], pa[fr][ks2], o[fr][df], 0, 0, 0);
  }
  __builtin_amdgcn_s_setprio(0);
}

// ---------------------------------------------------------------------------
// Flash attention, 2-tile software pipeline (T15 mechanism): phase A issues
// QK^T(t+1) MFMAs BEFORE softmax(t)+PV(t), so the matrix pipe works tile t+1
// while the VALU/TRANS runs tile t's softmax, and PV MFMAs cover the global
// prefetches. Static A/B register sets (sfA/sfB); single kf/vp sets reused.
// Grid (S/128, NH, B), 256 thr = 4 waves, wave owns 32 q-rows.
// ---------------------------------------------------------------------------
#define NT (S_LEN / 64)
__launch_bounds__(256, 2)
__global__ void attn_kernel(const short* __restrict__ Q, const short* __restrict__ K,
                            const short* __restrict__ V, short* __restrict__ O,
                            int qs, int ks_, int os) {
  const int qt = blockIdx.x, h = blockIdx.y, b = blockIdx.z;
  const int kv = h >> 2;
  const int tid  = threadIdx.x;
  const int lane = tid & 63, w = tid >> 6;
  const int lr = lane & 15, lg = lane >> 4;

  __shared__ short Vt[2][64][72];   // [buf][d][kc-permuted]

  const int q0 = qt * 128 + w * 32;
  bf16x8 qa[2][2];
#pragma unroll
  for (int fr = 0; fr < 2; ++fr) {
    const short* qp = Q + (size_t)(b * S_LEN + q0 + fr * 16 + lr) * qs + h * HEAD_DIM + lg * 8;
    qa[fr][0] = *(const bf16x8*)qp;
    qa[fr][1] = *(const bf16x8*)(qp + 32);
  }

  f32x4 o[2][4] = {};
  float mrow[2] = {-1e30f, -1e30f};
  float msc[2]  = {-1e30f, -1e30f};
  float lsum[2] = {0.f, 0.f};

  const int vdb   = w * 16;
  const int cperm = (lane & 32) + ((lane >> 2) & 3) * 8 + ((lane >> 4) & 1) * 4 + (lane & 3);
  const short* vbase = V + ((size_t)(b * S_LEN) + lane) * ks_ + kv * HEAD_DIM + vdb;
  const short* kbase = K + (size_t)(b * S_LEN + lr) * ks_ + kv * HEAD_DIM + lg * 8;

  const float SC   = 0.125f * 1.4426950408889634f;   // HD^-0.5 * log2(e)
  const float THRR = 8.0f / SC;

  // ---- prologue: V(0) regs, K(0) frags, sfA = QK^T(0), K(1) frags ----
  bf16x8 vp0 = *(const bf16x8*)vbase;
  bf16x8 vp1 = *(const bf16x8*)(vbase + 8);
  bf16x8 kf[4][2];
  f32x4 sfA[2][4], sfB[2][4];
  load_kf(kf, kbase, 0, ks_);
  qkt_mfma(kf, qa, sfA);
  load_kf(kf, kbase, 1, ks_);

  for (int t = 0; t < NT; t += 2) {
    // ================= phase A: tile t =================
#pragma unroll
    for (int j = 0; j < 8; ++j) Vt[0][vdb + j][cperm] = vp0[j];
#pragma unroll
    for (int j = 0; j < 8; ++j) Vt[0][vdb + 8 + j][cperm] = vp1[j];
    __syncthreads();
    {  // prefetch V(t+1)  (t+1 < NT always: NT even)
      const short* vp = vbase + (size_t)(t + 1) * 64 * ks_;
      vp0 = *(const bf16x8*)vp;
      vp1 = *(const bf16x8*)(vp + 8);
    }
    qkt_mfma(kf, qa, sfB);                       // QK^T(t+1), uses kf=K(t+1)
    if (t + 2 < NT) load_kf(kf, kbase, t + 2, ks_);
    softmax_pv(sfA, Vt[0], o, mrow, msc, lsum, lr, lg, SC, THRR);

    // ================= phase B: tile t+1 =================
#pragma unroll
    for (int j = 0; j < 8; ++j) Vt[1][vdb + j][cperm] = vp0[j];
#pragma unroll
    for (int j = 0; j < 8; ++j) Vt[1][vdb + 8 + j][cperm] = vp1[j];
    __syncthreads();
    if (t + 2 < NT) {
      const short* vp = vbase + (size_t)(t + 2) * 64 * ks_;
      vp0 = *(const bf16x8*)vp;
      vp1 = *(const bf16x8*)(vp + 8);
      qkt_mfma(kf, qa, sfA);                     // QK^T(t+2), uses kf=K(t+2)
    }
    if (t + 3 < NT) load_kf(kf, kbase, t + 3, ks_);
    softmax_pv(sfB, Vt[1], o, mrow, msc, lsum, lr, lg, SC, THRR);
  }

  // ---- epilogue: combine lane-partial denominators once, then store ----
#pragma unroll
  for (int fr = 0; fr < 2; ++fr) {
    float ls = lsum[fr];
    ls += __shfl_xor(ls, 16);
    ls += __shfl_xor(ls, 32);
    const float invl = 1.0f / ls;
    const size_t orow = (size_t)(b * S_LEN + q0 + fr * 16 + lr) * os + h * HEAD_DIM;
#pragma unroll
    for (int df = 0; df < 4; ++df) {
      u32x2 pk;
      pk[0] = cvtpk(o[fr][df][0] * invl, o[fr][df][1] * invl);
      pk[1] = cvtpk(o[fr][df][2] * invl, o[fr][df][3] * invl);
      *(u32x2*)&O[orow + df * 16 + 4 * lg] = pk;
    }
  }
}

// ---------------------------------------------------------------------------
extern "C" void kernel_launch(void* const* d_in, const int* in_sizes, int n_in,
                              void* d_out, int out_size, void* d_ws, size_t ws_size,
                              hipStream_t stream) {
  (void)in_sizes; (void)n_in; (void)out_size;
  const float* hidden = (const float*)d_in[0];
  const float* wq = (const float*)d_in[1];
  const float* wk = (const float*)d_in[2];
  const float* wv = (const float*)d_in[3];
  const float* wo = (const float*)d_in[4];
  float* out = (float*)d_out;

  const int M = 2 * S_LEN;                        // 4096
  const size_t nHid  = (size_t)M * HIDDEN;        // 8388608
  const size_t nW    = (size_t)HIDDEN * HIDDEN;   // 4194304
  const size_t nWkv  = (size_t)KVD * HIDDEN;      // 1048576
  const size_t nWcat = nW + 2 * nWkv;             // 6291456  (wq|wk|wv rows)
  const int    NQKV  = HIDDEN + 2 * KVD;          // 3072
  const size_t nQKV  = (size_t)M * NQKV;          // 12582912

  const size_t fastElems = nHid + nWcat + nW + nQKV + nHid;  // 39845888
  if (ws_size >= fastElems * sizeof(short)) {
    short* hb   = (short*)d_ws;
    short* wcat = hb + nHid;          // [3072][2048]: wq rows, wk rows, wv rows
    short* wob  = wcat + nWcat;
    short* QKV  = wob + nW;           // [4096][3072]: Q | K | V
    short* AO   = QKV + nQKV;

    CvtArgs ca;
    ca.src[0] = hidden; ca.dst[0] = hb;            ca.cnt4[0] = (int)(nHid / 4);
    ca.src[1] = wq;     ca.dst[1] = wcat;          ca.cnt4[1] = (int)(nW / 4);
    ca.src[2] = wk;     ca.dst[2] = wcat + nW;     ca.cnt4[2] = (int)(nWkv / 4);
    ca.src[3] = wv;     ca.dst[3] = wcat + nW + nWkv; ca.cnt4[3] = (int)(nWkv / 4);
    ca.src[4] = wo;     ca.dst[4] = wob;           ca.cnt4[4] = (int)(nW / 4);
    const int total4 = (int)((nHid + nWcat + nW) / 4);
    cvt_bf16<<<2048, 256, 0, stream>>>(ca, total4);

    // fused QKV projection: [4096,3072] = hb @ wcat^T
    gemm_lds<short><<<dim3(NQKV / 128, 32), 256, 0, stream>>>(hb, wcat, QKV, M, NQKV, HIDDEN);
    // fused RoPE over Q(32 heads) + K(8 heads) = cols 0..2559
    const int rtot = M * 40 * 32;
    rope_kernel<40><<<(rtot + 255) / 256, 256, 0, stream>>>(QKV, NQKV, rtot);
    // attention: Q at col 0, K at col 2048, V at col 2560 of QKV
    attn_kernel<<<dim3(S_LEN / 128, N_HEADS, 2), 256, 0, stream>>>(
        QKV, QKV + HIDDEN, QKV + HIDDEN + KVD, AO, NQKV, NQKV, HIDDEN);
    // output projection
    gemm_lds<float><<<dim3(16, 32), 256, 0, stream>>>(AO, wob, out, M, HIDDEN, HIDDEN);
  } else {
    short* Qb = (short*)d_ws;
    short* Kb = Qb + nHid;
    short* Vb = Kb + (size_t)M * KVD;
    short* AO = Vb + (size_t)M * KVD;
    gemm_bt<float, short><<<dim3(16, 32), 256, 0, stream>>>(hidden, wq, Qb, M, HIDDEN, HIDDEN);
    gemm_bt<float, short><<<dim3(4, 32), 256, 0, stream>>>(hidden, wk, Kb, M, KVD, HIDDEN);
    gemm_bt<float, short><<<dim3(4, 32), 256, 0, stream>>>(hidden, wv, Vb, M, KVD, HIDDEN);
    const int rq = M * N_HEADS * 32, rk = M * N_KV * 32;
    rope_kernel<N_HEADS><<<(rq + 255) / 256, 256, 0, stream>>>(Qb, HIDDEN, rq);
    rope_kernel<N_KV><<<(rk + 255) / 256, 256, 0, stream>>>(Kb, KVD, rk);
    attn_kernel<<<dim3(S_LEN / 128, N_HEADS, 2), 256, 0, stream>>>(
        Qb, Kb, Vb, AO, HIDDEN, KVD, HIDDEN);
    gemm_bt<short, float><<<dim3(16, 32), 256, 0, stream>>>(AO, wo, out, M, HIDDEN, HIDDEN);
  }
}

// Round 8
// 289.130 us; speedup vs baseline: 2.6692x; 1.0134x over previous
//
#include <hip/hip_runtime.h>
#include <stdint.h>

typedef __attribute__((ext_vector_type(8))) short bf16x8;
typedef __attribute__((ext_vector_type(4))) short bf16x4;
typedef __attribute__((ext_vector_type(4))) float f32x4;
typedef __attribute__((ext_vector_type(4))) unsigned u32x4;
typedef __attribute__((ext_vector_type(2))) unsigned u32x2;

#define S_LEN 2048
#define HIDDEN 2048
#define N_HEADS 32
#define N_KV 8
#define HEAD_DIM 64
#define KVD (N_KV * HEAD_DIM)   // 512

__device__ __forceinline__ float bf2f(short u) {
  return __builtin_bit_cast(float, ((unsigned)(unsigned short)u) << 16);
}
__device__ __forceinline__ short f2bf(float f) {
  unsigned u = __builtin_bit_cast(unsigned, f);
  u += 0x7FFFu + ((u >> 16) & 1u);
  return (short)(u >> 16);
}
__device__ __forceinline__ unsigned cvtpk(float lo, float hi) {
  unsigned r;
  asm("v_cvt_pk_bf16_f32 %0, %1, %2" : "=v"(r) : "v"(lo), "v"(hi));
  return r;
}
__device__ __forceinline__ bf16x8 cvt8(f32x4 lo, f32x4 hi) {
  bf16x8 r;
#pragma unroll
  for (int j = 0; j < 4; ++j) { r[j] = f2bf(lo[j]); r[j + 4] = f2bf(hi[j]); }
  return r;
}
__device__ __forceinline__ void storeC(float* p, float v) { *p = v; }
__device__ __forceinline__ void storeC(short* p, float v) { *p = f2bf(v); }

__device__ __forceinline__ void gll16(const void* g, void* l) {
  __builtin_amdgcn_global_load_lds(
      (const __attribute__((address_space(1))) void*)g,
      (__attribute__((address_space(3))) void*)l, 16, 0, 0);
}

// ---------------------------------------------------------------------------
// fp32 -> bf16 bulk convert, 5 segments, grid-stride, float4 units.
// ---------------------------------------------------------------------------
struct CvtArgs {
  const float* src[5];
  short* dst[5];
  int cnt4[5];
};
__global__ void cvt_bf16(CvtArgs a, int total4) {
  int u = blockIdx.x * 256 + threadIdx.x;
  const int stride = gridDim.x * 256;
  for (; u < total4; u += stride) {
    int s = 0, off = u;
    while (off >= a.cnt4[s]) { off -= a.cnt4[s]; ++s; }
    f32x4 v = *(const f32x4*)(a.src[s] + (size_t)off * 4);
    bf16x4 r;
#pragma unroll
    for (int j = 0; j < 4; ++j) r[j] = f2bf(v[j]);
    *(bf16x4*)(a.dst[s] + (size_t)off * 4) = r;
  }
}

// ---------------------------------------------------------------------------
// FAST GEMM (m97 structure): C[M,N] = A[M,K] @ W[N,K]^T, bf16 in, bf16/fp32 out.
// 128x128 tile, BK=32, global_load_lds width=16 staging, linear LDS.
// NOTE: XCD swizzle tried in R7 and REVERTED — costs ~20us when operands are
// L2/L3-resident (T1 only pays when HBM-bound).
// ---------------------------------------------------------------------------
template <typename CT>
__launch_bounds__(256, 3)
__global__ void gemm_lds(const short* __restrict__ A, const short* __restrict__ W,
                         CT* __restrict__ C, int M, int N, int K) {
  __shared__ short As[128 * 32];
  __shared__ short Ws[128 * 32];
  const int tid  = threadIdx.x;
  const int lane = tid & 63;
  const int w    = tid >> 6;
  const int wm = w >> 1, wn = w & 1;
  const int lr = lane & 15, lg = lane >> 4;
  const int m0 = blockIdx.y * 128, n0 = blockIdx.x * 128;

  const size_t a0 = (size_t)(m0 + w * 16 + (lane >> 2)) * K + (lane & 3) * 8;
  const size_t a1 = a0 + (size_t)64 * K;
  const size_t b0 = (size_t)(n0 + w * 16 + (lane >> 2)) * K + (lane & 3) * 8;
  const size_t b1 = b0 + (size_t)64 * K;
  short* lA0 = &As[(w * 16) * 32];
  short* lA1 = &As[(64 + w * 16) * 32];
  short* lB0 = &Ws[(w * 16) * 32];
  short* lB1 = &Ws[(64 + w * 16) * 32];

  f32x4 acc[4][4] = {};

  for (int k0 = 0; k0 < K; k0 += 32) {
    __syncthreads();
    gll16(A + a0 + k0, lA0);
    gll16(A + a1 + k0, lA1);
    gll16(W + b0 + k0, lB0);
    gll16(W + b1 + k0, lB1);
    __syncthreads();
    bf16x8 af[4], bfr[4];
#pragma unroll
    for (int i = 0; i < 4; ++i) {
      af[i]  = *(const bf16x8*)&As[(wm * 64 + i * 16 + lr) * 32 + lg * 8];
      bfr[i] = *(const bf16x8*)&Ws[(wn * 64 + i * 16 + lr) * 32 + lg * 8];
    }
#pragma unroll
    for (int i = 0; i < 4; ++i)
#pragma unroll
      for (int j = 0; j < 4; ++j)
        acc[i][j] = __builtin_amdgcn_mfma_f32_16x16x32_bf16(af[i], bfr[j], acc[i][j], 0, 0, 0);
  }

#pragma unroll
  for (int i = 0; i < 4; ++i)
#pragma unroll
    for (int j = 0; j < 4; ++j) {
      const int row = m0 + wm * 64 + i * 16 + lg * 4;
      const int col = n0 + wn * 64 + j * 16 + lr;
#pragma unroll
      for (int r = 0; r < 4; ++r)
        storeC(&C[(size_t)(row + r) * N + col], acc[i][j][r]);
    }
}

// ---------------------------------------------------------------------------
// FALLBACK GEMM (register-staged, converts fp32 in flight).
// ---------------------------------------------------------------------------
template <typename AT, typename CT>
__launch_bounds__(256, 2)
__global__ void gemm_bt(const AT* __restrict__ A, const float* __restrict__ W,
                        CT* __restrict__ C, int M, int N, int K) {
  __shared__ short As[128][40];
  __shared__ short Ws[128][40];
  const int tid  = threadIdx.x;
  const int lane = tid & 63;
  const int wid  = tid >> 6;
  const int wm = wid >> 1, wn = wid & 1;
  const int lr = lane & 15, lg = lane >> 4;
  const int m0 = blockIdx.y * 128, n0 = blockIdx.x * 128;
  const int srow = tid >> 2;
  const int scol = (tid & 3) * 8;

  f32x4 acc[4][4] = {};
  const AT*    Ap = A + (size_t)(m0 + srow) * K + scol;
  const float* Wp = W + (size_t)(n0 + srow) * K + scol;

  for (int k0 = 0; k0 < K; k0 += 32) {
    bf16x8 a0, a1, b0, b1;
    if constexpr (sizeof(AT) == 4) {
      a0 = cvt8(*(const f32x4*)(Ap + k0), *(const f32x4*)(Ap + k0 + 4));
      a1 = cvt8(*(const f32x4*)(Ap + (size_t)64 * K + k0),
                *(const f32x4*)(Ap + (size_t)64 * K + k0 + 4));
    } else {
      a0 = *(const bf16x8*)(Ap + k0);
      a1 = *(const bf16x8*)(Ap + (size_t)64 * K + k0);
    }
    b0 = cvt8(*(const f32x4*)(Wp + k0), *(const f32x4*)(Wp + k0 + 4));
    b1 = cvt8(*(const f32x4*)(Wp + (size_t)64 * K + k0),
              *(const f32x4*)(Wp + (size_t)64 * K + k0 + 4));
    __syncthreads();
    *(bf16x8*)&As[srow][scol]      = a0;
    *(bf16x8*)&As[srow + 64][scol] = a1;
    *(bf16x8*)&Ws[srow][scol]      = b0;
    *(bf16x8*)&Ws[srow + 64][scol] = b1;
    __syncthreads();
    bf16x8 af[4], bfr[4];
#pragma unroll
    for (int i = 0; i < 4; ++i) {
      af[i]  = *(const bf16x8*)&As[wm * 64 + i * 16 + lr][lg * 8];
      bfr[i] = *(const bf16x8*)&Ws[wn * 64 + i * 16 + lr][lg * 8];
    }
#pragma unroll
    for (int i = 0; i < 4; ++i)
#pragma unroll
      for (int j = 0; j < 4; ++j)
        acc[i][j] = __builtin_amdgcn_mfma_f32_16x16x32_bf16(af[i], bfr[j], acc[i][j], 0, 0, 0);
  }
#pragma unroll
  for (int i = 0; i < 4; ++i)
#pragma unroll
    for (int j = 0; j < 4; ++j) {
      const int row = m0 + wm * 64 + i * 16 + lg * 4;
      const int col = n0 + wn * 64 + j * 16 + lr;
#pragma unroll
      for (int r = 0; r < 4; ++r)
        storeC(&C[(size_t)(row + r) * N + col], acc[i][j][r]);
    }
}

// ---------------------------------------------------------------------------
// RoPE, head h -> cols 64h..64h+63 of a [rows, rowstride] bf16 buffer.
// ---------------------------------------------------------------------------
template <int NH>
__global__ void rope_kernel(short* __restrict__ buf, int rowstride, int total) {
  int idx = blockIdx.x * 256 + threadIdx.x;
  if (idx >= total) return;
  const int i   = idx & 31;
  const int hh  = (idx >> 5) % NH;
  const int row = (idx >> 5) / NH;
  const int pos = row & (S_LEN - 1);
  const float invf = exp2f(-(float)i * (13.287712379549449f / 32.0f));
  const float ang  = (float)pos * invf;
  float sn, c;
  sincosf(ang, &sn, &c);
  size_t base = (size_t)row * rowstride + hh * 64;
  float x1 = bf2f(buf[base + i]);
  float x2 = bf2f(buf[base + i + 32]);
  buf[base + i]      = f2bf(x1 * c - x2 * sn);
  buf[base + i + 32] = f2bf(x2 * c + x1 * sn);
}

// ---------------------------------------------------------------------------
// Flash attention helpers (double-swapped MFMA layout).
// ---------------------------------------------------------------------------
__device__ __forceinline__ void qkt_mfma(const bf16x8 (&kf)[4][2],
                                         const bf16x8 (&qa)[2][2],
                                         f32x4 (&sf)[2][4]) {
  __builtin_amdgcn_s_setprio(1);
#pragma unroll
  for (int nf = 0; nf < 4; ++nf)
#pragma unroll
    for (int fr = 0; fr < 2; ++fr) {
      f32x4 t = {};
      t = __builtin_amdgcn_mfma_f32_16x16x32_bf16(kf[nf][0], qa[fr][0], t, 0, 0, 0);
      t = __builtin_amdgcn_mfma_f32_16x16x32_bf16(kf[nf][1], qa[fr][1], t, 0, 0, 0);
      sf[fr][nf] = t;
    }
  __builtin_amdgcn_s_setprio(0);
}

template <int KS>
__device__ __forceinline__ void load_kf(bf16x8 (&kf)[4][2], const short* kbase, int t) {
  const short* kp = kbase + (size_t)t * 64 * KS;
#pragma unroll
  for (int nf = 0; nf < 4; ++nf) {
    kf[nf][0] = *(const bf16x8*)(kp + (size_t)nf * 16 * KS);
    kf[nf][1] = *(const bf16x8*)(kp + (size_t)nf * 16 * KS + 32);
  }
}

// Early-issued PV B-operand reads (all 8 ds_read_b128 right after barrier).
__device__ __forceinline__ void load_vb(bf16x8 (&vb)[2][4], const short (*vt)[72],
                                        int lr, int lg) {
#pragma unroll
  for (int ks2 = 0; ks2 < 2; ++ks2)
#pragma unroll
    for (int df = 0; df < 4; ++df)
      vb[ks2][df] = *(const bf16x8*)&vt[df * 16 + lr][ks2 * 32 + lg * 8];
}

__device__ __forceinline__ void softmax_pv(
    f32x4 (&sf)[2][4], const bf16x8 (&vb)[2][4], f32x4 (&o)[2][4],
    float (&mrow)[2], float (&msc)[2], float (&lsum)[2],
    float SC, float THRR) {
  bf16x8 pa[2][2];
#pragma unroll
  for (int fr = 0; fr < 2; ++fr) {
    float lmax = fmaxf(fmaxf(sf[fr][0][0], sf[fr][0][1]), fmaxf(sf[fr][0][2], sf[fr][0][3]));
#pragma unroll
    for (int nf = 1; nf < 4; ++nf) {
      float m01 = fmaxf(sf[fr][nf][0], sf[fr][nf][1]);
      float m23 = fmaxf(sf[fr][nf][2], sf[fr][nf][3]);
      lmax = fmaxf(lmax, fmaxf(m01, m23));
    }
    // speculative defer-max: rare path only when lane-local max grew past thr
    if (!__all(lmax <= mrow[fr] + THRR)) {
      float mx = fmaxf(lmax, __shfl_xor(lmax, 16));
      mx = fmaxf(mx, __shfl_xor(mx, 32));
      const float mnew  = fmaxf(mrow[fr], mx);
      const float alpha = exp2f((mrow[fr] - mnew) * SC);
      mrow[fr] = mnew;
      msc[fr]  = mnew * SC;
      lsum[fr] *= alpha;
#pragma unroll
      for (int df = 0; df < 4; ++df) o[fr][df] *= alpha;
    }
    const float nm = msc[fr];
    float s = 0.f;
#pragma unroll
    for (int nf = 0; nf < 4; ++nf)
#pragma unroll
      for (int r = 0; r < 4; ++r) {
        float pv = exp2f(fmaf(sf[fr][nf][r], SC, -nm));
        sf[fr][nf][r] = pv;
        s += pv;
      }
    lsum[fr] += s;
#pragma unroll
    for (int ks2 = 0; ks2 < 2; ++ks2) {
      u32x4 pk;
      pk[0] = cvtpk(sf[fr][2 * ks2][0], sf[fr][2 * ks2][1]);
      pk[1] = cvtpk(sf[fr][2 * ks2][2], sf[fr][2 * ks2][3]);
      pk[2] = cvtpk(sf[fr][2 * ks2 + 1][0], sf[fr][2 * ks2 + 1][1]);
      pk[3] = cvtpk(sf[fr][2 * ks2 + 1][2], sf[fr][2 * ks2 + 1][3]);
      pa[fr][ks2] = __builtin_bit_cast(bf16x8, pk);
    }
  }
  __builtin_amdgcn_s_setprio(1);
#pragma unroll
  for (int ks2 = 0; ks2 < 2; ++ks2)
#pragma unroll
    for (int fr = 0; fr < 2; ++fr)
#pragma unroll
      for (int df = 0; df < 4; ++df)
        o[fr][df] = __builtin_amdgcn_mfma_f32_16x16x32_bf16(vb[ks2][df], pa[fr][ks2], o[fr][df], 0, 0, 0);
  __builtin_amdgcn_s_setprio(0);
}

// ---------------------------------------------------------------------------
// Flash attention, 2-tile software pipeline: phase issues QK^T(t+1) BEFORE
// softmax(t)+PV(t). Compile-time strides QS/KS/OS fold addressing to
// base+immediate. V-fragment ds_reads issued right after the barrier.
// Grid (S/128, NH, B), 256 thr = 4 waves, wave owns 32 q-rows.
// ---------------------------------------------------------------------------
#define NT (S_LEN / 64)
template <int QS, int KS, int OS>
__launch_bounds__(256, 2)
__global__ void attn_kernel(const short* __restrict__ Q, const short* __restrict__ K,
                            const short* __restrict__ V, short* __restrict__ O) {
  const int qt = blockIdx.x, h = blockIdx.y, b = blockIdx.z;
  const int kv = h >> 2;
  const int tid  = threadIdx.x;
  const int lane = tid & 63, w = tid >> 6;
  const int lr = lane & 15, lg = lane >> 4;

  __shared__ short Vt[2][64][72];   // [buf][d][kc-permuted]

  const int q0 = qt * 128 + w * 32;
  bf16x8 qa[2][2];
#pragma unroll
  for (int fr = 0; fr < 2; ++fr) {
    const short* qp = Q + (size_t)(b * S_LEN + q0 + fr * 16 + lr) * QS + h * HEAD_DIM + lg * 8;
    qa[fr][0] = *(const bf16x8*)qp;
    qa[fr][1] = *(const bf16x8*)(qp + 32);
  }

  f32x4 o[2][4] = {};
  float mrow[2] = {-1e30f, -1e30f};
  float msc[2]  = {-1e30f, -1e30f};
  float lsum[2] = {0.f, 0.f};

  const int vdb   = w * 16;
  const int cperm = (lane & 32) + ((lane >> 2) & 3) * 8 + ((lane >> 4) & 1) * 4 + (lane & 3);
  const short* vbase = V + ((size_t)(b * S_LEN) + lane) * KS + kv * HEAD_DIM + vdb;
  const short* kbase = K + (size_t)(b * S_LEN + lr) * KS + kv * HEAD_DIM + lg * 8;

  const float SC   = 0.125f * 1.4426950408889634f;   // HD^-0.5 * log2(e)
  const float THRR = 8.0f / SC;

  // ---- prologue ----
  bf16x8 vp0 = *(const bf16x8*)vbase;
  bf16x8 vp1 = *(const bf16x8*)(vbase + 8);
  bf16x8 kf[4][2];
  bf16x8 vbA[2][4], vbB[2][4];
  f32x4 sfA[2][4], sfB[2][4];
  load_kf<KS>(kf, kbase, 0);
  qkt_mfma(kf, qa, sfA);
  load_kf<KS>(kf, kbase, 1);

  for (int t = 0; t < NT; t += 2) {
    // ================= phase A: tile t =================
#pragma unroll
    for (int j = 0; j < 8; ++j) Vt[0][vdb + j][cperm] = vp0[j];
#pragma unroll
    for (int j = 0; j < 8; ++j) Vt[0][vdb + 8 + j][cperm] = vp1[j];
    __syncthreads();
    load_vb(vbA, Vt[0], lr, lg);                 // 8 ds_read issued early
    {  // prefetch V(t+1)  (t+1 < NT always: NT even)
      const short* vp = vbase + (size_t)(t + 1) * 64 * KS;
      vp0 = *(const bf16x8*)vp;
      vp1 = *(const bf16x8*)(vp + 8);
    }
    qkt_mfma(kf, qa, sfB);                       // QK^T(t+1), uses kf=K(t+1)
    if (t + 2 < NT) load_kf<KS>(kf, kbase, t + 2);
    softmax_pv(sfA, vbA, o, mrow, msc, lsum, SC, THRR);

    // ================= phase B: tile t+1 =================
#pragma unroll
    for (int j = 0; j < 8; ++j) Vt[1][vdb + j][cperm] = vp0[j];
#pragma unroll
    for (int j = 0; j < 8; ++j) Vt[1][vdb + 8 + j][cperm] = vp1[j];
    __syncthreads();
    load_vb(vbB, Vt[1], lr, lg);
    if (t + 2 < NT) {
      const short* vp = vbase + (size_t)(t + 2) * 64 * KS;
      vp0 = *(const bf16x8*)vp;
      vp1 = *(const bf16x8*)(vp + 8);
      qkt_mfma(kf, qa, sfA);                     // QK^T(t+2), uses kf=K(t+2)
    }
    if (t + 3 < NT) load_kf<KS>(kf, kbase, t + 3);
    softmax_pv(sfB, vbB, o, mrow, msc, lsum, SC, THRR);
  }

  // ---- epilogue: combine lane-partial denominators once, then store ----
#pragma unroll
  for (int fr = 0; fr < 2; ++fr) {
    float ls = lsum[fr];
    ls += __shfl_xor(ls, 16);
    ls += __shfl_xor(ls, 32);
    const float invl = 1.0f / ls;
    const size_t orow = (size_t)(b * S_LEN + q0 + fr * 16 + lr) * OS + h * HEAD_DIM;
#pragma unroll
    for (int df = 0; df < 4; ++df) {
      u32x2 pk;
      pk[0] = cvtpk(o[fr][df][0] * invl, o[fr][df][1] * invl);
      pk[1] = cvtpk(o[fr][df][2] * invl, o[fr][df][3] * invl);
      *(u32x2*)&O[orow + df * 16 + 4 * lg] = pk;
    }
  }
}

// ---------------------------------------------------------------------------
extern "C" void kernel_launch(void* const* d_in, const int* in_sizes, int n_in,
                              void* d_out, int out_size, void* d_ws, size_t ws_size,
                              hipStream_t stream) {
  (void)in_sizes; (void)n_in; (void)out_size;
  const float* hidden = (const float*)d_in[0];
  const float* wq = (const float*)d_in[1];
  const float* wk = (const float*)d_in[2];
  const float* wv = (const float*)d_in[3];
  const float* wo = (const float*)d_in[4];
  float* out = (float*)d_out;

  const int M = 2 * S_LEN;                        // 4096
  const size_t nHid  = (size_t)M * HIDDEN;        // 8388608
  const size_t nW    = (size_t)HIDDEN * HIDDEN;   // 4194304
  const size_t nWkv  = (size_t)KVD * HIDDEN;      // 1048576
  const size_t nWcat = nW + 2 * nWkv;             // 6291456  (wq|wk|wv rows)
  const int    NQKV  = HIDDEN + 2 * KVD;          // 3072
  const size_t nQKV  = (size_t)M * NQKV;          // 12582912

  const size_t fastElems = nHid + nWcat + nW + nQKV + nHid;  // 39845888
  if (ws_size >= fastElems * sizeof(short)) {
    short* hb   = (short*)d_ws;
    short* wcat = hb + nHid;          // [3072][2048]: wq rows, wk rows, wv rows
    short* wob  = wcat + nWcat;
    short* QKV  = wob + nW;           // [4096][3072]: Q | K | V
    short* AO   = QKV + nQKV;

    CvtArgs ca;
    ca.src[0] = hidden; ca.dst[0] = hb;            ca.cnt4[0] = (int)(nHid / 4);
    ca.src[1] = wq;     ca.dst[1] = wcat;          ca.cnt4[1] = (int)(nW / 4);
    ca.src[2] = wk;     ca.dst[2] = wcat + nW;     ca.cnt4[2] = (int)(nWkv / 4);
    ca.src[3] = wv;     ca.dst[3] = wcat + nW + nWkv; ca.cnt4[3] = (int)(nWkv / 4);
    ca.src[4] = wo;     ca.dst[4] = wob;           ca.cnt4[4] = (int)(nW / 4);
    const int total4 = (int)((nHid + nWcat + nW) / 4);
    cvt_bf16<<<2048, 256, 0, stream>>>(ca, total4);

    // fused QKV projection: [4096,3072] = hb @ wcat^T
    gemm_lds<short><<<dim3(NQKV / 128, 32), 256, 0, stream>>>(hb, wcat, QKV, M, NQKV, HIDDEN);
    // fused RoPE over Q(32 heads) + K(8 heads) = cols 0..2559
    const int rtot = M * 40 * 32;
    rope_kernel<40><<<(rtot + 255) / 256, 256, 0, stream>>>(QKV, NQKV, rtot);
    // attention: Q at col 0, K at col 2048, V at col 2560 of QKV
    attn_kernel<3072, 3072, HIDDEN><<<dim3(S_LEN / 128, N_HEADS, 2), 256, 0, stream>>>(
        QKV, QKV + HIDDEN, QKV + HIDDEN + KVD, AO);
    // output projection
    gemm_lds<float><<<dim3(16, 32), 256, 0, stream>>>(AO, wob, out, M, HIDDEN, HIDDEN);
  } else {
    short* Qb = (short*)d_ws;
    short* Kb = Qb + nHid;
    short* Vb = Kb + (size_t)M * KVD;
    short* AO = Vb + (size_t)M * KVD;
    gemm_bt<float, short><<<dim3(16, 32), 256, 0, stream>>>(hidden, wq, Qb, M, HIDDEN, HIDDEN);
    gemm_bt<float, short><<<dim3(4, 32), 256, 0, stream>>>(hidden, wk, Kb, M, KVD, HIDDEN);
    gemm_bt<float, short><<<dim3(4, 32), 256, 0, stream>>>(hidden, wv, Vb, M, KVD, HIDDEN);
    const int rq = M * N_HEADS * 32, rk = M * N_KV * 32;
    rope_kernel<N_HEADS><<<(rq + 255) / 256, 256, 0, stream>>>(Qb, HIDDEN, rq);
    rope_kernel<N_KV><<<(rk + 255) / 256, 256, 0, stream>>>(Kb, KVD, rk);
    attn_kernel<HIDDEN, KVD, HIDDEN><<<dim3(S_LEN / 128, N_HEADS, 2), 256, 0, stream>>>(
        Qb, Kb, Vb, AO);
    gemm_bt<short, float><<<dim3(16, 32), 256, 0, stream>>>(AO, wo, out, M, HIDDEN, HIDDEN);
  }
}